// Round 17
// baseline (226.636 us; speedup 1.0000x reference)
//
#include <hip/hip_runtime.h>

#define NPTS 60000
#define NXG 256
#define NCELL 65536
#define MAXP 12000
#define MAXPP 32
#define NROWS (MAXP*MAXPP)

typedef float f32x32 __attribute__((ext_vector_type(32)));
typedef float f32x4  __attribute__((ext_vector_type(4)));
typedef short s16x8  __attribute__((ext_vector_type(8)));

__device__ __forceinline__ short to_bf16(float f){
  unsigned u = __float_as_uint(f);
  unsigned r = (u + 0x7FFFu + ((u>>16)&1u)) >> 16;
  return (short)r;
}
// order-preserving float<->uint for atomicMax/Min
__device__ __forceinline__ unsigned mapf(float f){
  unsigned u = __float_as_uint(f);
  return (u & 0x80000000u) ? ~u : (u | 0x80000000u);
}
__device__ __forceinline__ float unmapf(unsigned u){
  unsigned b = (u & 0x80000000u) ? (u ^ 0x80000000u) : ~u;
  return __uint_as_float(b);
}

// ---------------- prep: zero ws + conv/mlp weights bf16 + FMN pattern ----------------
__global__ __launch_bounds__(256) void prep(uint4* __restrict__ p1, size_t n1,
                                            uint4* __restrict__ p2, size_t n2,
                                            const float* __restrict__ w0, const float* __restrict__ w1,
                                            const float* __restrict__ w2, short* __restrict__ wh,
                                            const float* __restrict__ mw1, const float* __restrict__ mw2,
                                            short* __restrict__ w1h, short* __restrict__ w2h,
                                            uint4* __restrict__ fmn, size_t nfmn){
  size_t idx = (size_t)blockIdx.x*256 + threadIdx.x;
  size_t stride = (size_t)gridDim.x*256;
  const uint4 z = make_uint4(0,0,0,0);
  const uint4 ff = make_uint4(0xFFFFFFFFu,0xFFFFFFFFu,0xFFFFFFFFu,0xFFFFFFFFu);
  for (size_t k=idx; k<n1; k+=stride) p1[k]=z;
  for (size_t k=idx; k<n2; k+=stride) p2[k]=z;
  for (size_t k=idx; k<nfmn; k+=stride) fmn[k]=ff;
  for (size_t k=idx; k<3*36864; k+=stride){
    int l = (int)(k / 36864), r = (int)(k - (size_t)l*36864);
    const float* w = (l==0)? w0 : ((l==1)? w1 : w2);
    int ic = r & 63, oc = (r>>6)&63, tap = r>>12;
    wh[k] = to_bf16(w[(oc*64+ic)*9 + tap]);
  }
  for (size_t k=idx; k<2048; k+=stride){           // w1h: [k(32, zero-pad>=10)][oc]
    int kk = (int)(k>>6), oc = (int)(k&63);
    w1h[k] = (kk<10) ? to_bf16(mw1[kk*64+oc]) : (short)0;
  }
  for (size_t k=idx; k<4096; k+=stride)            // w2h: [k(64)][oc]
    w2h[k] = to_bf16(mw2[k]);
}

// ---------------- pillarize (mask dtype probed per-block) ----------------
__global__ void compute_pid(const float* __restrict__ pts, const void* __restrict__ maskp,
                            int* __restrict__ pid, int* __restrict__ ccnt){
  __shared__ int cf32, cbig;
  if (threadIdx.x==0){ cf32=0; cbig=0; }
  __syncthreads();
  {
    int lf=0, lb=0;
    const unsigned* mu = (const unsigned*)maskp;
    for (int k=0;k<4;k++){
      unsigned x = mu[threadIdx.x*4+k];
      if (x==0x3f800000u) lf++;
      else if (x>1u) lb++;
    }
    if (lf) atomicAdd(&cf32, lf);
    if (lb) atomicAdd(&cbig, lb);
  }
  __syncthreads();
  int mode = (cf32>64) ? 2 : ((cbig>0) ? 1 : 0);
  int i = blockIdx.x*blockDim.x + threadIdx.x;
  if (i>=NPTS) return;
  int b = blockIdx.y;
  int gi = b*NPTS+i;
  bool m;
  if (mode==0)      m = ((const int*)maskp)[gi]!=0;
  else if (mode==1) m = ((const unsigned char*)maskp)[gi]!=0;
  else              m = ((const float*)maskp)[gi]!=0.f;
  int cell = -1;
  if (m){
    float x = pts[(size_t)gi*5+0], y = pts[(size_t)gi*5+1];
    int ix = (int)((x - (-32.0f)) / 0.25f);
    ix = ix<0?0:(ix>255?255:ix);
    int iy = (int)((y - (-32.0f)) / 0.25f);
    iy = iy<0?0:(iy>255?255:iy);
    cell = iy*NXG + ix;
    atomicAdd(&ccnt[b*NCELL+cell], 1);
  }
  pid[gi] = cell;
}

// ---------------- parallel occupancy scan ----------------
__global__ __launch_bounds__(256) void scan_a(const int* __restrict__ ccnt,
                                              int2* __restrict__ bpart){
  int b = blockIdx.y, blk = blockIdx.x, t = threadIdx.x;
  int4 v = *(const int4*)&ccnt[b*NCELL + blk*1024 + t*4];
  int occ = (v.x>0)+(v.y>0)+(v.z>0)+(v.w>0);
  int cnt = v.x+v.y+v.z+v.w;
  #pragma unroll
  for (int off=32; off>0; off>>=1){
    occ += __shfl_xor(occ, off, 64);
    cnt += __shfl_xor(cnt, off, 64);
  }
  __shared__ int so[4], sc[4];
  int wv = t>>6, lane = t&63;
  if (lane==0){ so[wv]=occ; sc[wv]=cnt; }
  __syncthreads();
  if (t==0) bpart[b*64+blk] = make_int2(so[0]+so[1]+so[2]+so[3], sc[0]+sc[1]+sc[2]+sc[3]);
}

__global__ __launch_bounds__(256) void scan_b(const int* __restrict__ ccnt,
    const int2* __restrict__ bpart,
    int* __restrict__ crank, int* __restrict__ cstart, int* __restrict__ pcell,
    int* __restrict__ misc, int* __restrict__ heavy){
  __shared__ int swo[4], swc[4], sk[4];
  __shared__ int bo_, bc_;
  int b = blockIdx.y, blk = blockIdx.x, t = threadIdx.x;
  int wv = t>>6, lane = t&63;
  if (t < 64){
    int2 p = bpart[b*64+t];
    int po = (t<blk)? p.x : 0;
    int pc = (t<blk)? p.y : 0;
    int to = p.x;
    int tc = p.y;
    #pragma unroll
    for (int off=32; off>0; off>>=1){
      po += __shfl_xor(po, off, 64);
      pc += __shfl_xor(pc, off, 64);
      to += __shfl_xor(to, off, 64);
      tc += __shfl_xor(tc, off, 64);
    }
    if (t==0){
      bo_ = po; bc_ = pc;
      if (blk==0){
        misc[1+b] = (to < MAXP) ? to : MAXP;
        misc[5+b] = tc;               // total masked points
      }
    }
  }
  int4 v = *(const int4*)&ccnt[b*NCELL + blk*1024 + t*4];
  int occ = (v.x>0)+(v.y>0)+(v.z>0)+(v.w>0);
  int cnt = v.x+v.y+v.z+v.w;
  int io = occ, ic = cnt;
  #pragma unroll
  for (int off=1; off<64; off<<=1){
    int ao = __shfl_up(io, off, 64);
    int ac = __shfl_up(ic, off, 64);
    if (lane >= off){ io += ao; ic += ac; }
  }
  if (lane==63){ swo[wv]=io; swc[wv]=ic; }
  __syncthreads();
  int wvo=0, wvc=0;
  #pragma unroll
  for (int w2=0; w2<4; w2++){
    if (w2<wv){ wvo += swo[w2]; wvc += swc[w2]; }
  }
  int eo = bo_ + wvo + io - occ;
  int ec = bc_ + wvc + ic - cnt;
  int kept = 0;
  int cellb = blk*1024 + t*4;
  int vv[4] = {v.x,v.y,v.z,v.w};
  #pragma unroll
  for (int j=0;j<4;j++){
    int c = cellb+j; int val = vv[j];
    if (val>0){
      crank[b*NCELL+c]=eo; cstart[b*NCELL+c]=ec;
      if (eo<MAXP){
        pcell[b*MAXP+eo]=c;
        kept += (val<MAXPP)? val : MAXPP;
        if (val>MAXPP){
          int hi = atomicAdd(&heavy[b],1);
          if (hi<64) heavy[2 + b*64 + hi] = c;
        }
      }
      eo++; ec+=val;
    }
  }
  #pragma unroll
  for (int off=32; off>0; off>>=1) kept += __shfl_xor(kept, off, 64);
  if (lane==0) sk[wv]=kept;
  __syncthreads();
  if (t==0) atomicAdd(&misc[3+b], sk[0]+sk[1]+sk[2]+sk[3]);
}

// ---------------- scatter: write CPTS directly at pillar-sorted position ----------------
// CPTS[pos]: [x,y,z,i1][i2,gx,gy,rid][dx,dy,dz,0]  (quad2 filled by moments)
__global__ void scatter_cpts(const float* __restrict__ pts, const int* __restrict__ pid,
    const int* __restrict__ ccnt, const int* __restrict__ crank, const int* __restrict__ cstart,
    int* __restrict__ ctmp, int* __restrict__ plist,
    float* __restrict__ cpts, float* __restrict__ psum){
  int i = blockIdx.x*blockDim.x + threadIdx.x;
  if (i>=NPTS) return;
  int b = blockIdx.y;
  int gi = b*NPTS+i;
  int cell = pid[gi];
  if (cell<0) return;
  int bc = b*NCELL+cell;
  int pos = cstart[bc] + atomicAdd(&ctmp[bc],1);
  plist[b*NPTS+pos] = i;
  int cnt = ccnt[bc], r = crank[bc];
  int rid = (r<MAXP && cnt<=MAXPP) ? r : -1;
  const float* qp = &pts[(size_t)gi*5];
  float x=qp[0], y=qp[1], z=qp[2], i1=qp[3], i2=qp[4];
  float gx = -32.0f + ((float)(cell&255)+0.5f)*0.25f;
  float gy = -32.0f + ((float)(cell>>8)+0.5f)*0.25f;
  float4* cp = (float4*)&cpts[(size_t)(b*NPTS+pos)*12];
  cp[0] = make_float4(x,y,z,i1);
  cp[1] = make_float4(i2,gx,gy,__int_as_float(rid));
  if (rid>=0){
    float* s = &psum[(size_t)(b*MAXP+rid)*4];
    atomicAdd(s+0,x); atomicAdd(s+1,y); atomicAdd(s+2,z); atomicAdd(s+3,1.f);
  }
}

// heavy cells (>32 pts): select first-32-by-original-index, patch CPTS rid + psum
__global__ void heavy_select(const float* __restrict__ pts,
    const int* __restrict__ ccnt, const int* __restrict__ crank,
    const int* __restrict__ cstart, const int* __restrict__ plist,
    const int* __restrict__ heavy, float* __restrict__ cpts, float* __restrict__ psum){
  int b = blockIdx.y;
  int hn = heavy[b]; if (hn>64) hn=64;
  if ((int)blockIdx.x >= hn) return;
  int cell = heavy[2 + b*64 + blockIdx.x];
  int bc = b*NCELL+cell;
  int cnt = ccnt[bc], start = cstart[bc], pr = crank[bc];
  for (int e=threadIdx.x; e<cnt; e+=blockDim.x){
    int pe = plist[b*NPTS+start+e];
    int rank=0;
    for (int k=0;k<cnt;k++) rank += (plist[b*NPTS+start+k] < pe);
    if (rank<MAXPP && pr<MAXP){
      cpts[(size_t)(b*NPTS+start+e)*12 + 7] = __int_as_float(pr);
      const float* qp = &pts[(size_t)(b*NPTS+pe)*5];
      float* s = &psum[(size_t)(b*MAXP+pr)*4];
      atomicAdd(s+0,qp[0]); atomicAdd(s+1,qp[1]); atomicAdd(s+2,qp[2]); atomicAdd(s+3,1.f);
    }
  }
}

// ---------------- global aug moments (65 register accumulators) + centroid writeback ----
#define MM_ACC(K,V) { if ((K)<32) m0[(K)&31]+=(V); else if ((K)<64) m1[((K)-32)&31]+=(V); else m2+=(V); }
__global__ __launch_bounds__(256) void moments(float* __restrict__ cpts,
    const float* __restrict__ psum, const int* __restrict__ misc,
    float* __restrict__ lstat){
  int b = blockIdx.y;
  int n = misc[5+b];
  f32x32 m0, m1; float m2 = 0.f;
  #pragma unroll
  for (int j=0;j<32;j++){ m0[j]=0.f; m1[j]=0.f; }
  for (int pos = blockIdx.x*256+threadIdx.x; pos<n; pos += gridDim.x*256){
    float4* cp = (float4*)&cpts[(size_t)(b*NPTS+pos)*12];
    float4 f1 = cp[0], f2 = cp[1];
    int rid = __float_as_int(f2.w);
    if (rid<0) continue;
    float4 mc = *(const float4*)&psum[(size_t)(b*MAXP+rid)*4];
    float inv = 1.f/fmaxf(mc.w,1.f);
    float dx = f1.x-mc.x*inv, dy = f1.y-mc.y*inv, dz = f1.z-mc.z*inv;
    cp[2] = make_float4(dx,dy,dz,0.f);
    float aug[10] = {f1.x,f1.y,f1.z,f1.w,f2.x, dx,dy,dz, f2.y,f2.z};
    #pragma unroll
    for (int d=0; d<10; d++){
      #pragma unroll
      for (int e=d; e<10; e++){
        const int k = d*10 - d*(d-1)/2 + (e-d);
        MM_ACC(k, aug[d]*aug[e]);
      }
      const int kl = 55+d;
      MM_ACC(kl, aug[d]);
    }
  }
  int lane = threadIdx.x & 63;
  int rep = ((blockIdx.x*256+threadIdx.x)>>6) & 15;
  float* dst = &lstat[(size_t)(rep*2+b)*65];
  #pragma unroll
  for (int j=0;j<32;j++){
    float v = m0[j];
    #pragma unroll
    for (int off=32; off>0; off>>=1) v += __shfl_xor(v, off, 64);
    if (lane==0) atomicAdd(&dst[j], v);
  }
  #pragma unroll
  for (int j=0;j<32;j++){
    float v = m1[j];
    #pragma unroll
    for (int off=32; off>0; off>>=1) v += __shfl_xor(v, off, 64);
    if (lane==0) atomicAdd(&dst[32+j], v);
  }
  {
    float v = m2;
    #pragma unroll
    for (int off=32; off>0; off>>=1) v += __shfl_xor(v, off, 64);
    if (lane==0) atomicAdd(&dst[64], v);
  }
}

// ---------------- point MLP via MFMA + fused segmented max/min + BN2 stats ----------
#define MFMA16(A,B,C) __builtin_amdgcn_mfma_f32_16x16x32_bf16(A,B,C,0,0,0)

__global__ __launch_bounds__(256) void point_mlp(const float* __restrict__ cpts,
    const int* __restrict__ misc,
    const float* __restrict__ w1, const float* __restrict__ b1,
    const float* __restrict__ g1, const float* __restrict__ be1,
    const short* __restrict__ w1h, const short* __restrict__ w2h,
    const float* __restrict__ lstat, float* __restrict__ l2stat,
    unsigned* __restrict__ fmxU, unsigned* __restrict__ fmnU){
  __shared__ float sM[65];
  __shared__ float sBN1[128];
  __shared__ short zT[4][16*72];
  const int b = blockIdx.y;
  const int t = threadIdx.x;
  for (int e=t; e<65; e+=256){
    float s=0.f;
    for (int r=0;r<16;r++) s += lstat[(size_t)(r*2+b)*65+e];
    sM[e]=s;
  }
  __syncthreads();
  if (t < 64){
    int c = t;
    float wcol[10];
    #pragma unroll
    for (int d=0;d<10;d++) wcol[d] = w1[d*64+c];
    float b1c = b1[c];
    float nk = (float)misc[3+b];
    const float N = (float)NROWS;
    float pad = N - nk;
    float lw = 0.f;
    #pragma unroll
    for (int d=0;d<10;d++) lw += sM[55+d]*wcol[d];
    float s = nk*b1c + lw;
    float qq = nk*b1c*b1c + 2.f*b1c*lw;
    #pragma unroll
    for (int d=0; d<10; d++){
      #pragma unroll
      for (int e=d; e<10; e++){
        float m = sM[d*10 - d*(d-1)/2 + (e-d)];
        qq += ((d==e)?1.f:2.f)*m*wcol[d]*wcol[e];
      }
    }
    float St = s + pad*b1c;
    float Qt = qq + pad*b1c*b1c;
    float mu = St/N;
    float var = fmaxf(Qt/N - mu*mu, 0.f);
    float sc = g1[c]*rsqrtf(var+1e-5f);
    float sh = be1[c]-mu*sc;
    sBN1[c]=sc; sBN1[64+c]=b1c*sc+sh;
  }
  __syncthreads();
  const int lane = t & 63, wv = t >> 6;
  const int colx = lane & 15;
  const int kq = lane >> 4, kb = kq*8;
  s16x8 w1f0, w1f1, w1f2, w1f3;
  s16x8 a2f0, a2f1, a2f2, a2f3;
  s16x8 b2f0, b2f1, b2f2, b2f3;
  #pragma unroll
  for (int j=0;j<8;j++){
    w1f0[j]=w1h[(kb+j)*64 +  0+colx]; w1f1[j]=w1h[(kb+j)*64 + 16+colx];
    w1f2[j]=w1h[(kb+j)*64 + 32+colx]; w1f3[j]=w1h[(kb+j)*64 + 48+colx];
    a2f0[j]=w2h[(kb+j)*64 +  0+colx]; a2f1[j]=w2h[(kb+j)*64 + 16+colx];
    a2f2[j]=w2h[(kb+j)*64 + 32+colx]; a2f3[j]=w2h[(kb+j)*64 + 48+colx];
    b2f0[j]=w2h[(32+kb+j)*64 +  0+colx]; b2f1[j]=w2h[(32+kb+j)*64 + 16+colx];
    b2f2[j]=w2h[(32+kb+j)*64 + 32+colx]; b2f3[j]=w2h[(32+kb+j)*64 + 48+colx];
  }
  float sc1v0=sBN1[colx],    sh1v0=sBN1[64+colx];
  float sc1v1=sBN1[16+colx], sh1v1=sBN1[80+colx];
  float sc1v2=sBN1[32+colx], sh1v2=sBN1[96+colx];
  float sc1v3=sBN1[48+colx], sh1v3=sBN1[112+colx];
  const int n = misc[5+b];
  const int ntiles = (n+15)>>4;
  short* myZ = zT[wv];
  f32x4 s24={0.f,0.f,0.f,0.f}, q24=s24;
  for (int tile = blockIdx.x*4 + wv; tile < ntiles; tile += gridDim.x*4){
    int pos0 = tile*16;
    int pos = pos0 + colx;
    float aug[10];
    #pragma unroll
    for (int d=0;d<10;d++) aug[d]=0.f;
    if (pos < n){
      const float4* cp = (const float4*)&cpts[(size_t)(b*NPTS+pos)*12];
      float4 f1 = cp[0], f2 = cp[1], f3 = cp[2];
      aug[0]=f1.x; aug[1]=f1.y; aug[2]=f1.z; aug[3]=f1.w; aug[4]=f2.x;
      aug[5]=f3.x; aug[6]=f3.y; aug[7]=f3.z;
      aug[8]=f2.y; aug[9]=f2.z;
    }
    s16x8 af;
    #pragma unroll
    for (int j=0;j<8;j++){
      float v = 0.f;
      if (kq==0) v = aug[j];
      else if (kq==1 && j<2) v = aug[8+j];
      af[j] = to_bf16(v);
    }
    f32x4 y0={0.f,0.f,0.f,0.f}, y1=y0, y2=y0, y3=y0;
    y0 = MFMA16(af, w1f0, y0);
    y1 = MFMA16(af, w1f1, y1);
    y2 = MFMA16(af, w1f2, y2);
    y3 = MFMA16(af, w1f3, y3);
    #pragma unroll
    for (int m=0;m<4;m++){
      int pr = (kq*4+m)*72;
      myZ[pr +  0+colx] = to_bf16(fmaxf(y0[m]*sc1v0+sh1v0, 0.f));
      myZ[pr + 16+colx] = to_bf16(fmaxf(y1[m]*sc1v1+sh1v1, 0.f));
      myZ[pr + 32+colx] = to_bf16(fmaxf(y2[m]*sc1v2+sh1v2, 0.f));
      myZ[pr + 48+colx] = to_bf16(fmaxf(y3[m]*sc1v3+sh1v3, 0.f));
    }
    s16x8 az0 = *(const s16x8*)&myZ[colx*72 + kb];
    s16x8 az1 = *(const s16x8*)&myZ[colx*72 + 32 + kb];
    f32x4 t0={0.f,0.f,0.f,0.f}, t1=t0, t2=t0, t3=t0;
    t0 = MFMA16(az0, a2f0, t0); t0 = MFMA16(az1, b2f0, t0);
    t1 = MFMA16(az0, a2f1, t1); t1 = MFMA16(az1, b2f1, t1);
    t2 = MFMA16(az0, a2f2, t2); t2 = MFMA16(az1, b2f2, t2);
    t3 = MFMA16(az0, a2f3, t3); t3 = MFMA16(az1, b2f3, t3);
    // segmented max/min over this lane's 4 consecutive points (channels colx+16g)
    int cur = -1;
    f32x4 tmx={-1e30f,-1e30f,-1e30f,-1e30f}, tmn={1e30f,1e30f,1e30f,1e30f};
    #pragma unroll
    for (int m=0;m<4;m++){
      int pm = pos0 + kq*4 + m;
      int rid = -1;
      if (pm < n) rid = __float_as_int(cpts[(size_t)(b*NPTS+pm)*12 + 7]);
      if (rid != cur){
        if (cur >= 0){
          size_t base = (size_t)(b*MAXP+cur)*64;
          atomicMax(&fmxU[base+ 0+colx], mapf(tmx[0]));
          atomicMax(&fmxU[base+16+colx], mapf(tmx[1]));
          atomicMax(&fmxU[base+32+colx], mapf(tmx[2]));
          atomicMax(&fmxU[base+48+colx], mapf(tmx[3]));
          atomicMin(&fmnU[base+ 0+colx], mapf(tmn[0]));
          atomicMin(&fmnU[base+16+colx], mapf(tmn[1]));
          atomicMin(&fmnU[base+32+colx], mapf(tmn[2]));
          atomicMin(&fmnU[base+48+colx], mapf(tmn[3]));
        }
        cur = rid;
        tmx[0]=-1e30f; tmx[1]=-1e30f; tmx[2]=-1e30f; tmx[3]=-1e30f;
        tmn[0]= 1e30f; tmn[1]= 1e30f; tmn[2]= 1e30f; tmn[3]= 1e30f;
      }
      if (rid >= 0){
        float v0=t0[m], v1=t1[m], v2=t2[m], v3=t3[m];
        tmx[0]=fmaxf(tmx[0],v0); tmn[0]=fminf(tmn[0],v0);
        tmx[1]=fmaxf(tmx[1],v1); tmn[1]=fminf(tmn[1],v1);
        tmx[2]=fmaxf(tmx[2],v2); tmn[2]=fminf(tmn[2],v2);
        tmx[3]=fmaxf(tmx[3],v3); tmn[3]=fminf(tmn[3],v3);
        s24[0]+=v0; q24[0]+=v0*v0;
        s24[1]+=v1; q24[1]+=v1*v1;
        s24[2]+=v2; q24[2]+=v2*v2;
        s24[3]+=v3; q24[3]+=v3*v3;
      }
    }
    if (cur >= 0){
      size_t base = (size_t)(b*MAXP+cur)*64;
      atomicMax(&fmxU[base+ 0+colx], mapf(tmx[0]));
      atomicMax(&fmxU[base+16+colx], mapf(tmx[1]));
      atomicMax(&fmxU[base+32+colx], mapf(tmx[2]));
      atomicMax(&fmxU[base+48+colx], mapf(tmx[3]));
      atomicMin(&fmnU[base+ 0+colx], mapf(tmn[0]));
      atomicMin(&fmnU[base+16+colx], mapf(tmn[1]));
      atomicMin(&fmnU[base+32+colx], mapf(tmn[2]));
      atomicMin(&fmnU[base+48+colx], mapf(tmn[3]));
    }
  }
  int rep = (blockIdx.x*4 + wv) & 15;
  float* L = &l2stat[(size_t)((rep*2+b)*2+0)*64];
  atomicAdd(&L[ 0+colx], s24[0]);
  atomicAdd(&L[16+colx], s24[1]);
  atomicAdd(&L[32+colx], s24[2]);
  atomicAdd(&L[48+colx], s24[3]);
  float* Q = &l2stat[(size_t)((rep*2+b)*2+1)*64];
  atomicAdd(&Q[ 0+colx], q24[0]);
  atomicAdd(&Q[16+colx], q24[1]);
  atomicAdd(&Q[32+colx], q24[2]);
  atomicAdd(&Q[48+colx], q24[3]);
}

// ---------------- BN2 params (in-block) + BN2+relu on pillar max/min -> bf16 BEV ----------
__global__ __launch_bounds__(256) void scatter_bev(
    const float* __restrict__ w1, const float* __restrict__ b1,
    const float* __restrict__ g1, const float* __restrict__ be1,
    const float* __restrict__ w2, const float* __restrict__ b2,
    const float* __restrict__ g2, const float* __restrict__ be2,
    const float* __restrict__ lstat, const float* __restrict__ l2stat,
    const unsigned* __restrict__ fmxU, const unsigned* __restrict__ fmnU,
    const int* __restrict__ pcell, const int* __restrict__ misc,
    short* __restrict__ bevh){
  __shared__ float M[65];
  __shared__ float z0s[64];
  __shared__ float sBN2[128];
  const int b = blockIdx.y;
  for (int e=threadIdx.x; e<65; e+=256){
    float s=0.f;
    for (int r=0;r<16;r++) s += lstat[(size_t)(r*2+b)*65+e];
    M[e]=s;
  }
  __syncthreads();
  if (threadIdx.x < 64){
    int c = threadIdx.x;
    float wcol[10];
    #pragma unroll
    for (int d=0;d<10;d++) wcol[d] = w1[d*64+c];
    float b1c = b1[c];
    float nk = (float)misc[3+b];
    const float N = (float)NROWS;
    float pad = N - nk;
    float lw = 0.f;
    #pragma unroll
    for (int d=0;d<10;d++) lw += M[55+d]*wcol[d];
    float s = nk*b1c + lw;
    float qq = nk*b1c*b1c + 2.f*b1c*lw;
    #pragma unroll
    for (int d=0; d<10; d++){
      #pragma unroll
      for (int e=d; e<10; e++){
        float m = M[d*10 - d*(d-1)/2 + (e-d)];
        qq += ((d==e)?1.f:2.f)*m*wcol[d]*wcol[e];
      }
    }
    float St = s + pad*b1c;
    float Qt = qq + pad*b1c*b1c;
    float mu = St/N;
    float var = fmaxf(Qt/N - mu*mu, 0.f);
    float sc1 = g1[c]*rsqrtf(var+1e-5f);
    float sh1 = be1[c]-mu*sc1;
    z0s[c] = fmaxf(b1c*sc1+sh1, 0.f);
  }
  __syncthreads();
  if (threadIdx.x < 64){
    int c = threadIdx.x;
    float nk = (float)misc[3+b];
    const float N = (float)NROWS;
    float pad = N - nk;
    float t0 = b2[c];
    for (int i2=0;i2<64;i2++) t0 += z0s[i2]*w2[(size_t)i2*64+c];
    float s2 = pad*t0, q2 = pad*t0*t0;
    for (int r=0;r<16;r++){
      s2 += l2stat[(size_t)((r*2+b)*2+0)*64+c];
      q2 += l2stat[(size_t)((r*2+b)*2+1)*64+c];
    }
    float m2 = s2/N;
    float v2 = fmaxf(q2/N - m2*m2, 0.f);
    float sc2 = g2[c]*rsqrtf(v2+1e-5f);
    sBN2[c]=sc2; sBN2[64+c]=be2[c]-m2*sc2;
  }
  __syncthreads();
  const int npil = misc[1+b];
  for (int tid = blockIdx.x*256+threadIdx.x; tid < 64*MAXP; tid += gridDim.x*256){
    int c = tid & 63;
    int p = tid >> 6;
    if (p >= npil) break;
    float sc2 = sBN2[c], sh2 = sBN2[64+c];
    size_t idx = (size_t)(b*MAXP+p)*64 + c;
    float tv = (sc2 >= 0.f) ? unmapf(fmxU[idx]) : unmapf(fmnU[idx]);
    float v = fmaxf(sc2*tv+sh2, 0.f);
    int cell = pcell[b*MAXP+p];
    bevh[((size_t)((b<<16) + cell))*64 + c] = to_bf16(v);
  }
}

// ---------------- fused MFMA conv3x3: one block per 16x16 tile, all 64 oc, 512 thr ----------
__global__ __launch_bounds__(512,4) void conv_mfma(const short* __restrict__ xh,
    const short* __restrict__ wh, const float* __restrict__ bias,
    const float* __restrict__ pstat, const float* __restrict__ pg, const float* __restrict__ pbe,
    short* __restrict__ outh, float* __restrict__ outf,
    float* __restrict__ stat){
  __shared__ short sX[324*40];
  __shared__ short sW[576*40];
  __shared__ float sBN[128];
  __shared__ float ss[64], sq[64];
  const int tX = blockIdx.x*16, tY = blockIdx.y*16;
  const int b = blockIdx.z;
  const int t = threadIdx.x;
  const int lane = t & 63, wv = t >> 6;
  const int colx = lane & 15;
  const int kb = (lane >> 4) * 8;
  const int ocb = (wv >> 2) * 32;
  const int ry  = (wv & 3) * 4;
  if (t < 64){ ss[t]=0.f; sq[t]=0.f; }
  if (t >= 64 && t < 128 && pstat){
    int c = t-64;
    const float n = 131072.f;
    float m = pstat[c]/n;
    float v = fmaxf(pstat[64+c]/n - m*m, 0.f);
    float sc = pg[c]*rsqrtf(v+1e-5f);
    sBN[c]=sc; sBN[64+c]=pbe[c]-m*sc;
  }

  f32x4 a00={0.f,0.f,0.f,0.f}, a01=a00, a02=a00, a03=a00;
  f32x4 a10=a00, a11=a00, a12=a00, a13=a00;

  for (int h=0; h<2; ++h){
    __syncthreads();
    for (int e=t; e<1296; e+=512){
      int px = e>>2, j = e&3;
      int yy = px/18, xx = px - yy*18;
      int gy = tY+yy-1, gx = tX+xx-1;
      uint4 v = make_uint4(0,0,0,0);
      if ((unsigned)gy<256u && (unsigned)gx<256u){
        v = *(const uint4*)&xh[((size_t)((b<<16) + (gy<<8) + gx))*64 + h*32 + j*8];
        if (pstat){
          unsigned arr[4] = {v.x, v.y, v.z, v.w};
          #pragma unroll
          for (int j2=0;j2<4;j2++){
            unsigned wrd = arr[j2];
            int ch = h*32 + j*8 + j2*2;
            float lo = __uint_as_float(wrd<<16);
            float hi = __uint_as_float(wrd & 0xffff0000u);
            lo = fmaxf(lo*sBN[ch]+sBN[64+ch], 0.f);
            hi = fmaxf(hi*sBN[ch+1]+sBN[64+ch+1], 0.f);
            arr[j2] = (unsigned)(unsigned short)to_bf16(lo) |
                      (((unsigned)(unsigned short)to_bf16(hi))<<16);
          }
          v = make_uint4(arr[0],arr[1],arr[2],arr[3]);
        }
      }
      *(uint4*)&sX[px*40 + j*8] = v;
    }
    for (int e=t; e<2304; e+=512){
      int row = e>>2, j = e&3;
      int tap = row>>6, oc = row&63;
      uint4 v = *(const uint4*)&wh[(size_t)tap*4096 + oc*64 + h*32 + j*8];
      *(uint4*)&sW[row*40 + j*8] = v;
    }
    __syncthreads();
    #pragma unroll
    for (int tap=0; tap<9; ++tap){
      const int dy = tap/3, dx = tap - dy*3;
      s16x8 wA = *(const s16x8*)&sW[(tap*64 + ocb +  0 + colx)*40 + kb];
      s16x8 wB = *(const s16x8*)&sW[(tap*64 + ocb + 16 + colx)*40 + kb];
      s16x8 x0 = *(const s16x8*)&sX[((ry+0+dy)*18 + colx+dx)*40 + kb];
      s16x8 x1 = *(const s16x8*)&sX[((ry+1+dy)*18 + colx+dx)*40 + kb];
      s16x8 x2 = *(const s16x8*)&sX[((ry+2+dy)*18 + colx+dx)*40 + kb];
      s16x8 x3 = *(const s16x8*)&sX[((ry+3+dy)*18 + colx+dx)*40 + kb];
      a00 = MFMA16(wA,x0,a00); a01 = MFMA16(wA,x1,a01);
      a02 = MFMA16(wA,x2,a02); a03 = MFMA16(wA,x3,a03);
      a10 = MFMA16(wB,x0,a10); a11 = MFMA16(wB,x1,a11);
      a12 = MFMA16(wB,x2,a12); a13 = MFMA16(wB,x3,a13);
    }
  }
  const int ocl = (lane>>4)*4;
  #define DOG(G, A0,A1,A2,A3) { \
    const int oc0g = ocb + G*16 + ocl; \
    float bj0=bias[oc0g], bj1=bias[oc0g+1], bj2=bias[oc0g+2], bj3=bias[oc0g+3]; \
    float v00=A0[0]+bj0, v01=A0[1]+bj1, v02=A0[2]+bj2, v03=A0[3]+bj3; \
    float v10=A1[0]+bj0, v11=A1[1]+bj1, v12=A1[2]+bj2, v13=A1[3]+bj3; \
    float v20=A2[0]+bj0, v21=A2[1]+bj1, v22=A2[2]+bj2, v23=A2[3]+bj3; \
    float v30=A3[0]+bj0, v31=A3[1]+bj1, v32=A3[2]+bj2, v33=A3[3]+bj3; \
    float s0=v00+v10+v20+v30, q0=v00*v00+v10*v10+v20*v20+v30*v30; \
    float s1=v01+v11+v21+v31, q1=v01*v01+v11*v11+v21*v21+v31*v31; \
    float s2=v02+v12+v22+v32, q2=v02*v02+v12*v12+v22*v22+v32*v32; \
    float s3=v03+v13+v23+v33, q3=v03*v03+v13*v13+v23*v23+v33*v33; \
    s0+=__shfl_xor(s0,1,64); s0+=__shfl_xor(s0,2,64); s0+=__shfl_xor(s0,4,64); s0+=__shfl_xor(s0,8,64); \
    q0+=__shfl_xor(q0,1,64); q0+=__shfl_xor(q0,2,64); q0+=__shfl_xor(q0,4,64); q0+=__shfl_xor(q0,8,64); \
    s1+=__shfl_xor(s1,1,64); s1+=__shfl_xor(s1,2,64); s1+=__shfl_xor(s1,4,64); s1+=__shfl_xor(s1,8,64); \
    q1+=__shfl_xor(q1,1,64); q1+=__shfl_xor(q1,2,64); q1+=__shfl_xor(q1,4,64); q1+=__shfl_xor(q1,8,64); \
    s2+=__shfl_xor(s2,1,64); s2+=__shfl_xor(s2,2,64); s2+=__shfl_xor(s2,4,64); s2+=__shfl_xor(s2,8,64); \
    q2+=__shfl_xor(q2,1,64); q2+=__shfl_xor(q2,2,64); q2+=__shfl_xor(q2,4,64); q2+=__shfl_xor(q2,8,64); \
    s3+=__shfl_xor(s3,1,64); s3+=__shfl_xor(s3,2,64); s3+=__shfl_xor(s3,4,64); s3+=__shfl_xor(s3,8,64); \
    q3+=__shfl_xor(q3,1,64); q3+=__shfl_xor(q3,2,64); q3+=__shfl_xor(q3,4,64); q3+=__shfl_xor(q3,8,64); \
    if (colx==0){ \
      atomicAdd(&ss[oc0g],s0);   atomicAdd(&sq[oc0g],q0); \
      atomicAdd(&ss[oc0g+1],s1); atomicAdd(&sq[oc0g+1],q1); \
      atomicAdd(&ss[oc0g+2],s2); atomicAdd(&sq[oc0g+2],q2); \
      atomicAdd(&ss[oc0g+3],s3); atomicAdd(&sq[oc0g+3],q3); \
    } \
    if (outh){ \
      size_t pb = (size_t)((b<<16) + tX + colx); \
      *(short4*)&outh[(pb + ((tY+ry+0)<<8))*64 + oc0g] = make_short4(to_bf16(v00),to_bf16(v01),to_bf16(v02),to_bf16(v03)); \
      *(short4*)&outh[(pb + ((tY+ry+1)<<8))*64 + oc0g] = make_short4(to_bf16(v10),to_bf16(v11),to_bf16(v12),to_bf16(v13)); \
      *(short4*)&outh[(pb + ((tY+ry+2)<<8))*64 + oc0g] = make_short4(to_bf16(v20),to_bf16(v21),to_bf16(v22),to_bf16(v23)); \
      *(short4*)&outh[(pb + ((tY+ry+3)<<8))*64 + oc0g] = make_short4(to_bf16(v30),to_bf16(v31),to_bf16(v32),to_bf16(v33)); \
    } else { \
      size_t cb0 = (((size_t)(b*64+oc0g))<<16) + ((tY+ry)<<8) + tX + colx; \
      outf[cb0          ] = v00; outf[cb0+(1<<16)      ] = v01; outf[cb0+(2<<16)      ] = v02; outf[cb0+(3<<16)      ] = v03; \
      outf[cb0+256      ] = v10; outf[cb0+(1<<16)+256  ] = v11; outf[cb0+(2<<16)+256  ] = v12; outf[cb0+(3<<16)+256  ] = v13; \
      outf[cb0+512      ] = v20; outf[cb0+(1<<16)+512  ] = v21; outf[cb0+(2<<16)+512  ] = v22; outf[cb0+(3<<16)+512  ] = v23; \
      outf[cb0+768      ] = v30; outf[cb0+(1<<16)+768  ] = v31; outf[cb0+(2<<16)+768  ] = v32; outf[cb0+(3<<16)+768  ] = v33; \
    } \
  }
  DOG(0, a00,a01,a02,a03)
  DOG(1, a10,a11,a12,a13)
  #undef DOG
  __syncthreads();
  if (t < 64){
    atomicAdd(&stat[t],    ss[t]);
    atomicAdd(&stat[64+t], sq[t]);
  }
}

// bn_fin fused: computes sc/sh from raw stats in LDS, then applies BN+relu.
__global__ __launch_bounds__(256) void bn_apply(float* __restrict__ x, const float* __restrict__ bnst,
                                                const float* __restrict__ g, const float* __restrict__ be){
  __shared__ float sBN[128];
  if (threadIdx.x < 64){
    int c = threadIdx.x;
    const float n = 131072.f;
    float m = bnst[c]/n;
    float v = fmaxf(bnst[64+c]/n - m*m, 0.f);
    float sc = g[c]*rsqrtf(v+1e-5f);
    sBN[c]=sc; sBN[64+c]=be[c]-m*sc;
  }
  __syncthreads();
  size_t idx = (size_t)blockIdx.x*256 + threadIdx.x;
  size_t stride = (size_t)gridDim.x*256;
  float4* p = (float4*)x;
  for (size_t k=idx; k<2097152ULL; k+=stride){
    int c = (int)((k>>14)&63);
    float sc = sBN[c], sh = sBN[64+c];
    float4 v = p[k];
    v.x=fmaxf(v.x*sc+sh,0.f); v.y=fmaxf(v.y*sc+sh,0.f);
    v.z=fmaxf(v.z*sc+sh,0.f); v.w=fmaxf(v.w*sc+sh,0.f);
    p[k]=v;
  }
}

// ---------------- launch ----------------
extern "C" void kernel_launch(void* const* d_in, const int* in_sizes, int n_in,
                              void* d_out, int out_size, void* d_ws, size_t ws_size,
                              hipStream_t stream){
  const float* pts  = (const float*)d_in[0];
  const void*  mask = d_in[1];
  const float* w1 = (const float*)d_in[2];
  const float* b1 = (const float*)d_in[3];
  const float* g1 = (const float*)d_in[4];
  const float* be1= (const float*)d_in[5];
  const float* w2 = (const float*)d_in[6];
  const float* b2 = (const float*)d_in[7];
  const float* g2 = (const float*)d_in[8];
  const float* be2= (const float*)d_in[9];
  const float* cw[3]  = {(const float*)d_in[10],(const float*)d_in[14],(const float*)d_in[18]};
  const float* cb[3]  = {(const float*)d_in[11],(const float*)d_in[15],(const float*)d_in[19]};
  const float* cg[3]  = {(const float*)d_in[12],(const float*)d_in[16],(const float*)d_in[20]};
  const float* cbe[3] = {(const float*)d_in[13],(const float*)d_in[17],(const float*)d_in[21]};
  float* out = (float*)d_out;

  char* W = (char*)d_ws;
  size_t off = 0;
  auto A = [&](size_t n){ size_t r = off; off = (off + n + 255) & ~(size_t)255; return r; };
  short*    BIGH  = (short*)   (W + A((size_t)2*NCELL*64*2));
  short*    OUT1H = (short*)   (W + A((size_t)2*NCELL*64*2));
  int*      PID   = (int*)     (W + A((size_t)2*NPTS*4));
  int*      CRANK = (int*)     (W + A((size_t)2*NCELL*4));
  int*      CSTART= (int*)     (W + A((size_t)2*NCELL*4));
  int*      PLIST = (int*)     (W + A((size_t)2*NPTS*4));
  int*      PCELL = (int*)     (W + A((size_t)2*MAXP*4));
  float*    CPTS  = (float*)   (W + A((size_t)2*NPTS*12*4));
  unsigned* FMN   = (unsigned*)(W + A((size_t)2*MAXP*64*4));
  short*    WH    = (short*)   (W + A((size_t)3*36864*2));
  short*    W1H   = (short*)   (W + A((size_t)2048*2));
  short*    W2H   = (short*)   (W + A((size_t)4096*2));
  int2*     BPART = (int2*)    (W + A((size_t)2*64*8));
  // ---- zero block ----
  size_t zbeg = off;
  unsigned* FMX   = (unsigned*)(W + A((size_t)2*MAXP*64*4));
  int*      CCNT  = (int*)     (W + A((size_t)2*NCELL*4));
  int*      CTMP  = (int*)     (W + A((size_t)2*NCELL*4));
  float*    PSUM  = (float*)   (W + A((size_t)2*MAXP*16));
  float*    LSTAT = (float*)   (W + A((size_t)16*2*65*4));
  float*    L2STAT= (float*)   (W + A((size_t)16*2*2*64*4));
  float*    BNST  = (float*)   (W + A((size_t)3*256*4));
  int*      HEAVY = (int*)     (W + A((size_t)(2+2*64)*4));
  int*      MISC  = (int*)     (W + A(256));
  size_t zend = off;

  prep<<<2048,256,0,stream>>>((uint4*)BIGH, (size_t)2*NCELL*64*2/16,
                              (uint4*)(W+zbeg), (zend-zbeg)/16,
                              cw[0], cw[1], cw[2], WH, w1, w2, W1H, W2H,
                              (uint4*)FMN, (size_t)2*MAXP*64*4/16);

  dim3 perPt((NPTS+255)/256, 2);

  compute_pid<<<perPt,256,0,stream>>>(pts, mask, PID, CCNT);
  scan_a<<<dim3(64,2),256,0,stream>>>(CCNT, BPART);
  scan_b<<<dim3(64,2),256,0,stream>>>(CCNT, BPART, CRANK, CSTART, PCELL, MISC, HEAVY);
  scatter_cpts<<<perPt,256,0,stream>>>(pts, PID, CCNT, CRANK, CSTART, CTMP, PLIST, CPTS, PSUM);
  heavy_select<<<dim3(64,2),64,0,stream>>>(pts, CCNT, CRANK, CSTART, PLIST, HEAVY, CPTS, PSUM);
  moments<<<dim3(120,2),256,0,stream>>>(CPTS, PSUM, MISC, LSTAT);
  point_mlp<<<dim3(256,2),256,0,stream>>>(CPTS, MISC, w1, b1, g1, be1,
                                          W1H, W2H, LSTAT, L2STAT, FMX, FMN);
  scatter_bev<<<dim3(512,2),256,0,stream>>>(w1, b1, g1, be1, w2, b2, g2, be2,
                                            LSTAT, L2STAT, FMX, FMN, PCELL, MISC, BIGH);

  // conv1: BIGH -> OUT1H (bf16, raw) + stats BNST0
  conv_mfma<<<dim3(16,16,2),512,0,stream>>>(BIGH, WH, cb[0], nullptr, nullptr, nullptr,
                                            OUT1H, nullptr, BNST);
  // conv2: OUT1H (bn1+relu in-kernel from BNST0) -> BIGH + stats BNST1
  conv_mfma<<<dim3(16,16,2),512,0,stream>>>(OUT1H, WH+36864, cb[1], BNST, cg[0], cbe[0],
                                            BIGH, nullptr, BNST+256);
  // conv3: BIGH (bn2+relu from BNST1) -> d_out (fp32) + stats BNST2
  conv_mfma<<<dim3(16,16,2),512,0,stream>>>(BIGH, WH+2*36864, cb[2], BNST+256, cg[1], cbe[1],
                                            nullptr, out, BNST+512);
  bn_apply<<<2048,256,0,stream>>>(out, BNST+512, cg[2], cbe[2]);
}

// Round 18
// 216.233 us; speedup vs baseline: 1.0481x; 1.0481x over previous
//
#include <hip/hip_runtime.h>

#define NPTS 60000
#define NXG 256
#define NCELL 65536
#define MAXP 12000
#define MAXPP 32
#define NROWS (MAXP*MAXPP)

typedef float f32x32 __attribute__((ext_vector_type(32)));
typedef float f32x4  __attribute__((ext_vector_type(4)));
typedef short s16x8  __attribute__((ext_vector_type(8)));

__device__ __forceinline__ short to_bf16(float f){
  unsigned u = __float_as_uint(f);
  unsigned r = (u + 0x7FFFu + ((u>>16)&1u)) >> 16;
  return (short)r;
}
// order-preserving float<->uint for atomicMax/Min
__device__ __forceinline__ unsigned mapf(float f){
  unsigned u = __float_as_uint(f);
  return (u & 0x80000000u) ? ~u : (u | 0x80000000u);
}
__device__ __forceinline__ float unmapf(unsigned u){
  unsigned b = (u & 0x80000000u) ? (u ^ 0x80000000u) : ~u;
  return __uint_as_float(b);
}

// ---------------- prep: zero ws + conv/mlp weights bf16 + FMN pattern ----------------
__global__ __launch_bounds__(256) void prep(uint4* __restrict__ p1, size_t n1,
                                            uint4* __restrict__ p2, size_t n2,
                                            const float* __restrict__ w0, const float* __restrict__ w1,
                                            const float* __restrict__ w2, short* __restrict__ wh,
                                            const float* __restrict__ mw1, const float* __restrict__ mw2,
                                            short* __restrict__ w1h, short* __restrict__ w2h,
                                            uint4* __restrict__ fmn, size_t nfmn){
  size_t idx = (size_t)blockIdx.x*256 + threadIdx.x;
  size_t stride = (size_t)gridDim.x*256;
  const uint4 z = make_uint4(0,0,0,0);
  const uint4 ff = make_uint4(0xFFFFFFFFu,0xFFFFFFFFu,0xFFFFFFFFu,0xFFFFFFFFu);
  for (size_t k=idx; k<n1; k+=stride) p1[k]=z;
  for (size_t k=idx; k<n2; k+=stride) p2[k]=z;
  for (size_t k=idx; k<nfmn; k+=stride) fmn[k]=ff;
  for (size_t k=idx; k<3*36864; k+=stride){
    int l = (int)(k / 36864), r = (int)(k - (size_t)l*36864);
    const float* w = (l==0)? w0 : ((l==1)? w1 : w2);
    int ic = r & 63, oc = (r>>6)&63, tap = r>>12;
    wh[k] = to_bf16(w[(oc*64+ic)*9 + tap]);
  }
  for (size_t k=idx; k<2048; k+=stride){           // w1h: [k(32, zero-pad>=10)][oc]
    int kk = (int)(k>>6), oc = (int)(k&63);
    w1h[k] = (kk<10) ? to_bf16(mw1[kk*64+oc]) : (short)0;
  }
  for (size_t k=idx; k<4096; k+=stride)            // w2h: [k(64)][oc]
    w2h[k] = to_bf16(mw2[k]);
}

// ---------------- pillarize (mask dtype probed per-block) ----------------
__global__ void compute_pid(const float* __restrict__ pts, const void* __restrict__ maskp,
                            int* __restrict__ pid, int* __restrict__ ccnt){
  __shared__ int cf32, cbig;
  if (threadIdx.x==0){ cf32=0; cbig=0; }
  __syncthreads();
  {
    int lf=0, lb=0;
    const unsigned* mu = (const unsigned*)maskp;
    for (int k=0;k<4;k++){
      unsigned x = mu[threadIdx.x*4+k];
      if (x==0x3f800000u) lf++;
      else if (x>1u) lb++;
    }
    if (lf) atomicAdd(&cf32, lf);
    if (lb) atomicAdd(&cbig, lb);
  }
  __syncthreads();
  int mode = (cf32>64) ? 2 : ((cbig>0) ? 1 : 0);
  int i = blockIdx.x*blockDim.x + threadIdx.x;
  if (i>=NPTS) return;
  int b = blockIdx.y;
  int gi = b*NPTS+i;
  bool m;
  if (mode==0)      m = ((const int*)maskp)[gi]!=0;
  else if (mode==1) m = ((const unsigned char*)maskp)[gi]!=0;
  else              m = ((const float*)maskp)[gi]!=0.f;
  int cell = -1;
  if (m){
    float x = pts[(size_t)gi*5+0], y = pts[(size_t)gi*5+1];
    int ix = (int)((x - (-32.0f)) / 0.25f);
    ix = ix<0?0:(ix>255?255:ix);
    int iy = (int)((y - (-32.0f)) / 0.25f);
    iy = iy<0?0:(iy>255?255:iy);
    cell = iy*NXG + ix;
    atomicAdd(&ccnt[b*NCELL+cell], 1);
  }
  pid[gi] = cell;
}

// ---------------- parallel occupancy scan ----------------
__global__ __launch_bounds__(256) void scan_a(const int* __restrict__ ccnt,
                                              int2* __restrict__ bpart){
  int b = blockIdx.y, blk = blockIdx.x, t = threadIdx.x;
  int4 v = *(const int4*)&ccnt[b*NCELL + blk*1024 + t*4];
  int occ = (v.x>0)+(v.y>0)+(v.z>0)+(v.w>0);
  int cnt = v.x+v.y+v.z+v.w;
  #pragma unroll
  for (int off=32; off>0; off>>=1){
    occ += __shfl_xor(occ, off, 64);
    cnt += __shfl_xor(cnt, off, 64);
  }
  __shared__ int so[4], sc[4];
  int wv = t>>6, lane = t&63;
  if (lane==0){ so[wv]=occ; sc[wv]=cnt; }
  __syncthreads();
  if (t==0) bpart[b*64+blk] = make_int2(so[0]+so[1]+so[2]+so[3], sc[0]+sc[1]+sc[2]+sc[3]);
}

__global__ __launch_bounds__(256) void scan_b(const int* __restrict__ ccnt,
    const int2* __restrict__ bpart,
    int* __restrict__ crank, int* __restrict__ cstart, int* __restrict__ pcell,
    int* __restrict__ misc, int* __restrict__ heavy){
  __shared__ int swo[4], swc[4], sk[4];
  __shared__ int bo_, bc_;
  int b = blockIdx.y, blk = blockIdx.x, t = threadIdx.x;
  int wv = t>>6, lane = t&63;
  if (t < 64){
    int2 p = bpart[b*64+t];
    int po = (t<blk)? p.x : 0;
    int pc = (t<blk)? p.y : 0;
    int to = p.x;
    int tc = p.y;
    #pragma unroll
    for (int off=32; off>0; off>>=1){
      po += __shfl_xor(po, off, 64);
      pc += __shfl_xor(pc, off, 64);
      to += __shfl_xor(to, off, 64);
      tc += __shfl_xor(tc, off, 64);
    }
    if (t==0){
      bo_ = po; bc_ = pc;
      if (blk==0){
        misc[1+b] = (to < MAXP) ? to : MAXP;
        misc[5+b] = tc;               // total masked points
      }
    }
  }
  int4 v = *(const int4*)&ccnt[b*NCELL + blk*1024 + t*4];
  int occ = (v.x>0)+(v.y>0)+(v.z>0)+(v.w>0);
  int cnt = v.x+v.y+v.z+v.w;
  int io = occ, ic = cnt;
  #pragma unroll
  for (int off=1; off<64; off<<=1){
    int ao = __shfl_up(io, off, 64);
    int ac = __shfl_up(ic, off, 64);
    if (lane >= off){ io += ao; ic += ac; }
  }
  if (lane==63){ swo[wv]=io; swc[wv]=ic; }
  __syncthreads();
  int wvo=0, wvc=0;
  #pragma unroll
  for (int w2=0; w2<4; w2++){
    if (w2<wv){ wvo += swo[w2]; wvc += swc[w2]; }
  }
  int eo = bo_ + wvo + io - occ;
  int ec = bc_ + wvc + ic - cnt;
  int kept = 0;
  int cellb = blk*1024 + t*4;
  int vv[4] = {v.x,v.y,v.z,v.w};
  #pragma unroll
  for (int j=0;j<4;j++){
    int c = cellb+j; int val = vv[j];
    if (val>0){
      crank[b*NCELL+c]=eo; cstart[b*NCELL+c]=ec;
      if (eo<MAXP){
        pcell[b*MAXP+eo]=c;
        kept += (val<MAXPP)? val : MAXPP;
        if (val>MAXPP){
          int hi = atomicAdd(&heavy[b],1);
          if (hi<64) heavy[2 + b*64 + hi] = c;
        }
      }
      eo++; ec+=val;
    }
  }
  #pragma unroll
  for (int off=32; off>0; off>>=1) kept += __shfl_xor(kept, off, 64);
  if (lane==0) sk[wv]=kept;
  __syncthreads();
  if (t==0) atomicAdd(&misc[3+b], sk[0]+sk[1]+sk[2]+sk[3]);
}

// ---------------- scatter: write CPTS directly at pillar-sorted position ----------------
// CPTS[pos]: [x,y,z,i1][i2,gx,gy,rid][dx,dy,dz,0]  (quad2 filled by moments)
__global__ void scatter_cpts(const float* __restrict__ pts, const int* __restrict__ pid,
    const int* __restrict__ ccnt, const int* __restrict__ crank, const int* __restrict__ cstart,
    int* __restrict__ ctmp, int* __restrict__ plist,
    float* __restrict__ cpts, float* __restrict__ psum){
  int i = blockIdx.x*blockDim.x + threadIdx.x;
  if (i>=NPTS) return;
  int b = blockIdx.y;
  int gi = b*NPTS+i;
  int cell = pid[gi];
  if (cell<0) return;
  int bc = b*NCELL+cell;
  int pos = cstart[bc] + atomicAdd(&ctmp[bc],1);
  plist[b*NPTS+pos] = i;
  int cnt = ccnt[bc], r = crank[bc];
  int rid = (r<MAXP && cnt<=MAXPP) ? r : -1;
  const float* qp = &pts[(size_t)gi*5];
  float x=qp[0], y=qp[1], z=qp[2], i1=qp[3], i2=qp[4];
  float gx = -32.0f + ((float)(cell&255)+0.5f)*0.25f;
  float gy = -32.0f + ((float)(cell>>8)+0.5f)*0.25f;
  float4* cp = (float4*)&cpts[(size_t)(b*NPTS+pos)*12];
  cp[0] = make_float4(x,y,z,i1);
  cp[1] = make_float4(i2,gx,gy,__int_as_float(rid));
  if (rid>=0){
    float* s = &psum[(size_t)(b*MAXP+rid)*4];
    atomicAdd(s+0,x); atomicAdd(s+1,y); atomicAdd(s+2,z); atomicAdd(s+3,1.f);
  }
}

// heavy cells (>32 pts): select first-32-by-original-index, patch CPTS rid + psum
__global__ void heavy_select(const float* __restrict__ pts,
    const int* __restrict__ ccnt, const int* __restrict__ crank,
    const int* __restrict__ cstart, const int* __restrict__ plist,
    const int* __restrict__ heavy, float* __restrict__ cpts, float* __restrict__ psum){
  int b = blockIdx.y;
  int hn = heavy[b]; if (hn>64) hn=64;
  if ((int)blockIdx.x >= hn) return;
  int cell = heavy[2 + b*64 + blockIdx.x];
  int bc = b*NCELL+cell;
  int cnt = ccnt[bc], start = cstart[bc], pr = crank[bc];
  for (int e=threadIdx.x; e<cnt; e+=blockDim.x){
    int pe = plist[b*NPTS+start+e];
    int rank=0;
    for (int k=0;k<cnt;k++) rank += (plist[b*NPTS+start+k] < pe);
    if (rank<MAXPP && pr<MAXP){
      cpts[(size_t)(b*NPTS+start+e)*12 + 7] = __int_as_float(pr);
      const float* qp = &pts[(size_t)(b*NPTS+pe)*5];
      float* s = &psum[(size_t)(b*MAXP+pr)*4];
      atomicAdd(s+0,qp[0]); atomicAdd(s+1,qp[1]); atomicAdd(s+2,qp[2]); atomicAdd(s+3,1.f);
    }
  }
}

// ---------------- global aug moments (65 register accumulators) + centroid writeback ----
#define MM_ACC(K,V) { if ((K)<32) m0[(K)&31]+=(V); else if ((K)<64) m1[((K)-32)&31]+=(V); else m2+=(V); }
__global__ __launch_bounds__(256) void moments(float* __restrict__ cpts,
    const float* __restrict__ psum, const int* __restrict__ misc,
    float* __restrict__ lstat){
  int b = blockIdx.y;
  int n = misc[5+b];
  f32x32 m0, m1; float m2 = 0.f;
  #pragma unroll
  for (int j=0;j<32;j++){ m0[j]=0.f; m1[j]=0.f; }
  for (int pos = blockIdx.x*256+threadIdx.x; pos<n; pos += gridDim.x*256){
    float4* cp = (float4*)&cpts[(size_t)(b*NPTS+pos)*12];
    float4 f1 = cp[0], f2 = cp[1];
    int rid = __float_as_int(f2.w);
    if (rid<0) continue;
    float4 mc = *(const float4*)&psum[(size_t)(b*MAXP+rid)*4];
    float inv = 1.f/fmaxf(mc.w,1.f);
    float dx = f1.x-mc.x*inv, dy = f1.y-mc.y*inv, dz = f1.z-mc.z*inv;
    cp[2] = make_float4(dx,dy,dz,0.f);
    float aug[10] = {f1.x,f1.y,f1.z,f1.w,f2.x, dx,dy,dz, f2.y,f2.z};
    #pragma unroll
    for (int d=0; d<10; d++){
      #pragma unroll
      for (int e=d; e<10; e++){
        const int k = d*10 - d*(d-1)/2 + (e-d);
        MM_ACC(k, aug[d]*aug[e]);
      }
      const int kl = 55+d;
      MM_ACC(kl, aug[d]);
    }
  }
  int lane = threadIdx.x & 63;
  int rep = ((blockIdx.x*256+threadIdx.x)>>6) & 15;
  float* dst = &lstat[(size_t)(rep*2+b)*65];
  #pragma unroll
  for (int j=0;j<32;j++){
    float v = m0[j];
    #pragma unroll
    for (int off=32; off>0; off>>=1) v += __shfl_xor(v, off, 64);
    if (lane==0) atomicAdd(&dst[j], v);
  }
  #pragma unroll
  for (int j=0;j<32;j++){
    float v = m1[j];
    #pragma unroll
    for (int off=32; off>0; off>>=1) v += __shfl_xor(v, off, 64);
    if (lane==0) atomicAdd(&dst[32+j], v);
  }
  {
    float v = m2;
    #pragma unroll
    for (int off=32; off>0; off>>=1) v += __shfl_xor(v, off, 64);
    if (lane==0) atomicAdd(&dst[64], v);
  }
}

// ---------------- point-parallel MLP via MFMA: T[pos][64] = relu(bn1(Aug@W1))@W2 ----------
#define MFMA16(A,B,C) __builtin_amdgcn_mfma_f32_16x16x32_bf16(A,B,C,0,0,0)

__global__ __launch_bounds__(256) void point_mlp(const float* __restrict__ cpts,
    const int* __restrict__ misc,
    const float* __restrict__ w1, const float* __restrict__ b1,
    const float* __restrict__ g1, const float* __restrict__ be1,
    const short* __restrict__ w1h, const short* __restrict__ w2h,
    const float* __restrict__ lstat, float* __restrict__ tbuf){
  __shared__ float sM[65];
  __shared__ float sBN1[128];
  __shared__ short zT[4][16*72];
  const int b = blockIdx.y;
  const int t = threadIdx.x;
  for (int e=t; e<65; e+=256){
    float s=0.f;
    for (int r=0;r<16;r++) s += lstat[(size_t)(r*2+b)*65+e];
    sM[e]=s;
  }
  __syncthreads();
  if (t < 64){
    int c = t;
    float wcol[10];
    #pragma unroll
    for (int d=0;d<10;d++) wcol[d] = w1[d*64+c];
    float b1c = b1[c];
    float nk = (float)misc[3+b];
    const float N = (float)NROWS;
    float pad = N - nk;
    float lw = 0.f;
    #pragma unroll
    for (int d=0;d<10;d++) lw += sM[55+d]*wcol[d];
    float s = nk*b1c + lw;
    float qq = nk*b1c*b1c + 2.f*b1c*lw;
    #pragma unroll
    for (int d=0; d<10; d++){
      #pragma unroll
      for (int e=d; e<10; e++){
        float m = sM[d*10 - d*(d-1)/2 + (e-d)];
        qq += ((d==e)?1.f:2.f)*m*wcol[d]*wcol[e];
      }
    }
    float St = s + pad*b1c;
    float Qt = qq + pad*b1c*b1c;
    float mu = St/N;
    float var = fmaxf(Qt/N - mu*mu, 0.f);
    float sc = g1[c]*rsqrtf(var+1e-5f);
    float sh = be1[c]-mu*sc;
    sBN1[c]=sc; sBN1[64+c]=b1c*sc+sh;   // z = relu(y*sc + (b1*sc+sh)), y excludes b1
  }
  __syncthreads();
  const int lane = t & 63, wv = t >> 6;
  const int colx = lane & 15;
  const int kq = lane >> 4, kb = kq*8;
  s16x8 w1f0, w1f1, w1f2, w1f3;
  s16x8 a2f0, a2f1, a2f2, a2f3;
  s16x8 b2f0, b2f1, b2f2, b2f3;
  #pragma unroll
  for (int j=0;j<8;j++){
    w1f0[j]=w1h[(kb+j)*64 +  0+colx]; w1f1[j]=w1h[(kb+j)*64 + 16+colx];
    w1f2[j]=w1h[(kb+j)*64 + 32+colx]; w1f3[j]=w1h[(kb+j)*64 + 48+colx];
    a2f0[j]=w2h[(kb+j)*64 +  0+colx]; a2f1[j]=w2h[(kb+j)*64 + 16+colx];
    a2f2[j]=w2h[(kb+j)*64 + 32+colx]; a2f3[j]=w2h[(kb+j)*64 + 48+colx];
    b2f0[j]=w2h[(32+kb+j)*64 +  0+colx]; b2f1[j]=w2h[(32+kb+j)*64 + 16+colx];
    b2f2[j]=w2h[(32+kb+j)*64 + 32+colx]; b2f3[j]=w2h[(32+kb+j)*64 + 48+colx];
  }
  float sc1v0=sBN1[colx],    sh1v0=sBN1[64+colx];
  float sc1v1=sBN1[16+colx], sh1v1=sBN1[80+colx];
  float sc1v2=sBN1[32+colx], sh1v2=sBN1[96+colx];
  float sc1v3=sBN1[48+colx], sh1v3=sBN1[112+colx];
  const int n = misc[5+b];
  const int ntiles = (n+15)>>4;
  short* myZ = zT[wv];
  for (int tile = blockIdx.x*4 + wv; tile < ntiles; tile += gridDim.x*4){
    int pos0 = tile*16;
    int pos = pos0 + colx;
    float aug[10];
    #pragma unroll
    for (int d=0;d<10;d++) aug[d]=0.f;
    if (pos < n){
      const float4* cp = (const float4*)&cpts[(size_t)(b*NPTS+pos)*12];
      float4 f1 = cp[0], f2 = cp[1], f3 = cp[2];
      aug[0]=f1.x; aug[1]=f1.y; aug[2]=f1.z; aug[3]=f1.w; aug[4]=f2.x;
      aug[5]=f3.x; aug[6]=f3.y; aug[7]=f3.z;
      aug[8]=f2.y; aug[9]=f2.z;
    }
    s16x8 af;
    #pragma unroll
    for (int j=0;j<8;j++){
      float v = 0.f;
      if (kq==0) v = aug[j];
      else if (kq==1 && j<2) v = aug[8+j];
      af[j] = to_bf16(v);
    }
    f32x4 y0={0.f,0.f,0.f,0.f}, y1=y0, y2=y0, y3=y0;
    y0 = MFMA16(af, w1f0, y0);
    y1 = MFMA16(af, w1f1, y1);
    y2 = MFMA16(af, w1f2, y2);
    y3 = MFMA16(af, w1f3, y3);
    #pragma unroll
    for (int m=0;m<4;m++){
      int pr = (kq*4+m)*72;
      myZ[pr +  0+colx] = to_bf16(fmaxf(y0[m]*sc1v0+sh1v0, 0.f));
      myZ[pr + 16+colx] = to_bf16(fmaxf(y1[m]*sc1v1+sh1v1, 0.f));
      myZ[pr + 32+colx] = to_bf16(fmaxf(y2[m]*sc1v2+sh1v2, 0.f));
      myZ[pr + 48+colx] = to_bf16(fmaxf(y3[m]*sc1v3+sh1v3, 0.f));
    }
    s16x8 az0 = *(const s16x8*)&myZ[colx*72 + kb];
    s16x8 az1 = *(const s16x8*)&myZ[colx*72 + 32 + kb];
    f32x4 t0={0.f,0.f,0.f,0.f}, t1=t0, t2=t0, t3=t0;
    t0 = MFMA16(az0, a2f0, t0); t0 = MFMA16(az1, b2f0, t0);
    t1 = MFMA16(az0, a2f1, t1); t1 = MFMA16(az1, b2f1, t1);
    t2 = MFMA16(az0, a2f2, t2); t2 = MFMA16(az1, b2f2, t2);
    t3 = MFMA16(az0, a2f3, t3); t3 = MFMA16(az1, b2f3, t3);
    #pragma unroll
    for (int m=0;m<4;m++){
      int pm = pos0 + kq*4 + m;
      if (pm < n){
        float* dst = &tbuf[(size_t)(b*NPTS+pm)*64];
        dst[ 0+colx] = t0[m];
        dst[16+colx] = t1[m];
        dst[32+colx] = t2[m];
        dst[48+colx] = t3[m];
      }
    }
  }
}

// ---------------- segmented max/min over T (coalesced, atomic flush) ----------------
__global__ __launch_bounds__(256) void seg_max(const float* __restrict__ tbuf,
    const float* __restrict__ cpts, const int* __restrict__ misc,
    float* __restrict__ l2stat, unsigned* __restrict__ fmxU, unsigned* __restrict__ fmnU){
  const int b = blockIdx.y;
  const int lane = threadIdx.x & 63;
  const int n = misc[5+b];
  const int w = blockIdx.x*4 + (threadIdx.x>>6);
  float s2 = 0.f, q2 = 0.f;
  int p0 = w*16;
  if (p0 < n){
    int p1 = p0+16; if (p1>n) p1=n;
    int cur = -1;
    float tmax = -1e30f, tmin = 1e30f;
    for (int pos=p0; pos<p1; ++pos){
      int rid = __float_as_int(cpts[(size_t)(b*NPTS+pos)*12 + 7]);
      float tv = tbuf[(size_t)(b*NPTS+pos)*64 + lane];
      if (rid >= 0){
        if (rid != cur){
          if (cur >= 0){
            atomicMax(&fmxU[(size_t)(b*MAXP+cur)*64 + lane], mapf(tmax));
            atomicMin(&fmnU[(size_t)(b*MAXP+cur)*64 + lane], mapf(tmin));
          }
          cur = rid; tmax = -1e30f; tmin = 1e30f;
        }
        tmax = fmaxf(tmax, tv);
        tmin = fminf(tmin, tv);
        s2 += tv; q2 += tv*tv;
      }
    }
    if (cur >= 0){
      atomicMax(&fmxU[(size_t)(b*MAXP+cur)*64 + lane], mapf(tmax));
      atomicMin(&fmnU[(size_t)(b*MAXP+cur)*64 + lane], mapf(tmin));
    }
  }
  int rep = w & 15;
  atomicAdd(&l2stat[(size_t)((rep*2+b)*2+0)*64+lane], s2);
  atomicAdd(&l2stat[(size_t)((rep*2+b)*2+1)*64+lane], q2);
}

// ---------------- BN2 params (in-block) + BN2+relu on pillar max/min -> bf16 BEV ----------
__global__ __launch_bounds__(256) void scatter_bev(
    const float* __restrict__ w1, const float* __restrict__ b1,
    const float* __restrict__ g1, const float* __restrict__ be1,
    const float* __restrict__ w2, const float* __restrict__ b2,
    const float* __restrict__ g2, const float* __restrict__ be2,
    const float* __restrict__ lstat, const float* __restrict__ l2stat,
    const unsigned* __restrict__ fmxU, const unsigned* __restrict__ fmnU,
    const int* __restrict__ pcell, const int* __restrict__ misc,
    short* __restrict__ bevh){
  __shared__ float M[65];
  __shared__ float z0s[64];
  __shared__ float sBN2[128];
  const int b = blockIdx.y;
  for (int e=threadIdx.x; e<65; e+=256){
    float s=0.f;
    for (int r=0;r<16;r++) s += lstat[(size_t)(r*2+b)*65+e];
    M[e]=s;
  }
  __syncthreads();
  if (threadIdx.x < 64){
    int c = threadIdx.x;
    float wcol[10];
    #pragma unroll
    for (int d=0;d<10;d++) wcol[d] = w1[d*64+c];
    float b1c = b1[c];
    float nk = (float)misc[3+b];
    const float N = (float)NROWS;
    float pad = N - nk;
    float lw = 0.f;
    #pragma unroll
    for (int d=0;d<10;d++) lw += M[55+d]*wcol[d];
    float s = nk*b1c + lw;
    float qq = nk*b1c*b1c + 2.f*b1c*lw;
    #pragma unroll
    for (int d=0; d<10; d++){
      #pragma unroll
      for (int e=d; e<10; e++){
        float m = M[d*10 - d*(d-1)/2 + (e-d)];
        qq += ((d==e)?1.f:2.f)*m*wcol[d]*wcol[e];
      }
    }
    float St = s + pad*b1c;
    float Qt = qq + pad*b1c*b1c;
    float mu = St/N;
    float var = fmaxf(Qt/N - mu*mu, 0.f);
    float sc1 = g1[c]*rsqrtf(var+1e-5f);
    float sh1 = be1[c]-mu*sc1;
    z0s[c] = fmaxf(b1c*sc1+sh1, 0.f);
  }
  __syncthreads();
  if (threadIdx.x < 64){
    int c = threadIdx.x;
    float nk = (float)misc[3+b];
    const float N = (float)NROWS;
    float pad = N - nk;
    float t0 = b2[c];
    for (int i2=0;i2<64;i2++) t0 += z0s[i2]*w2[(size_t)i2*64+c];
    float s2 = pad*t0, q2 = pad*t0*t0;
    for (int r=0;r<16;r++){
      s2 += l2stat[(size_t)((r*2+b)*2+0)*64+c];
      q2 += l2stat[(size_t)((r*2+b)*2+1)*64+c];
    }
    float m2 = s2/N;
    float v2 = fmaxf(q2/N - m2*m2, 0.f);
    float sc2 = g2[c]*rsqrtf(v2+1e-5f);
    sBN2[c]=sc2; sBN2[64+c]=be2[c]-m2*sc2;
  }
  __syncthreads();
  const int npil = misc[1+b];
  for (int tid = blockIdx.x*256+threadIdx.x; tid < 64*MAXP; tid += gridDim.x*256){
    int c = tid & 63;
    int p = tid >> 6;
    if (p >= npil) break;
    float sc2 = sBN2[c], sh2 = sBN2[64+c];
    size_t idx = (size_t)(b*MAXP+p)*64 + c;
    float tv = (sc2 >= 0.f) ? unmapf(fmxU[idx]) : unmapf(fmnU[idx]);
    float v = fmaxf(sc2*tv+sh2, 0.f);
    int cell = pcell[b*MAXP+p];
    bevh[((size_t)((b<<16) + cell))*64 + c] = to_bf16(v);
  }
}

// ---------------- fused MFMA conv3x3: one block per 16x16 tile, all 64 oc, 512 thr ----------
__global__ __launch_bounds__(512,4) void conv_mfma(const short* __restrict__ xh,
    const short* __restrict__ wh, const float* __restrict__ bias,
    const float* __restrict__ pstat, const float* __restrict__ pg, const float* __restrict__ pbe,
    short* __restrict__ outh, float* __restrict__ outf,
    float* __restrict__ stat){
  __shared__ short sX[324*40];
  __shared__ short sW[576*40];
  __shared__ float sBN[128];
  __shared__ float ss[64], sq[64];
  const int tX = blockIdx.x*16, tY = blockIdx.y*16;
  const int b = blockIdx.z;
  const int t = threadIdx.x;
  const int lane = t & 63, wv = t >> 6;
  const int colx = lane & 15;
  const int kb = (lane >> 4) * 8;
  const int ocb = (wv >> 2) * 32;
  const int ry  = (wv & 3) * 4;
  if (t < 64){ ss[t]=0.f; sq[t]=0.f; }
  if (t >= 64 && t < 128 && pstat){
    int c = t-64;
    const float n = 131072.f;
    float m = pstat[c]/n;
    float v = fmaxf(pstat[64+c]/n - m*m, 0.f);
    float sc = pg[c]*rsqrtf(v+1e-5f);
    sBN[c]=sc; sBN[64+c]=pbe[c]-m*sc;
  }

  f32x4 a00={0.f,0.f,0.f,0.f}, a01=a00, a02=a00, a03=a00;
  f32x4 a10=a00, a11=a00, a12=a00, a13=a00;

  for (int h=0; h<2; ++h){
    __syncthreads();
    for (int e=t; e<1296; e+=512){
      int px = e>>2, j = e&3;
      int yy = px/18, xx = px - yy*18;
      int gy = tY+yy-1, gx = tX+xx-1;
      uint4 v = make_uint4(0,0,0,0);
      if ((unsigned)gy<256u && (unsigned)gx<256u){
        v = *(const uint4*)&xh[((size_t)((b<<16) + (gy<<8) + gx))*64 + h*32 + j*8];
        if (pstat){
          unsigned arr[4] = {v.x, v.y, v.z, v.w};
          #pragma unroll
          for (int j2=0;j2<4;j2++){
            unsigned wrd = arr[j2];
            int ch = h*32 + j*8 + j2*2;
            float lo = __uint_as_float(wrd<<16);
            float hi = __uint_as_float(wrd & 0xffff0000u);
            lo = fmaxf(lo*sBN[ch]+sBN[64+ch], 0.f);
            hi = fmaxf(hi*sBN[ch+1]+sBN[64+ch+1], 0.f);
            arr[j2] = (unsigned)(unsigned short)to_bf16(lo) |
                      (((unsigned)(unsigned short)to_bf16(hi))<<16);
          }
          v = make_uint4(arr[0],arr[1],arr[2],arr[3]);
        }
      }
      *(uint4*)&sX[px*40 + j*8] = v;
    }
    for (int e=t; e<2304; e+=512){
      int row = e>>2, j = e&3;
      int tap = row>>6, oc = row&63;
      uint4 v = *(const uint4*)&wh[(size_t)tap*4096 + oc*64 + h*32 + j*8];
      *(uint4*)&sW[row*40 + j*8] = v;
    }
    __syncthreads();
    #pragma unroll
    for (int tap=0; tap<9; ++tap){
      const int dy = tap/3, dx = tap - dy*3;
      s16x8 wA = *(const s16x8*)&sW[(tap*64 + ocb +  0 + colx)*40 + kb];
      s16x8 wB = *(const s16x8*)&sW[(tap*64 + ocb + 16 + colx)*40 + kb];
      s16x8 x0 = *(const s16x8*)&sX[((ry+0+dy)*18 + colx+dx)*40 + kb];
      s16x8 x1 = *(const s16x8*)&sX[((ry+1+dy)*18 + colx+dx)*40 + kb];
      s16x8 x2 = *(const s16x8*)&sX[((ry+2+dy)*18 + colx+dx)*40 + kb];
      s16x8 x3 = *(const s16x8*)&sX[((ry+3+dy)*18 + colx+dx)*40 + kb];
      a00 = MFMA16(wA,x0,a00); a01 = MFMA16(wA,x1,a01);
      a02 = MFMA16(wA,x2,a02); a03 = MFMA16(wA,x3,a03);
      a10 = MFMA16(wB,x0,a10); a11 = MFMA16(wB,x1,a11);
      a12 = MFMA16(wB,x2,a12); a13 = MFMA16(wB,x3,a13);
    }
  }
  const int ocl = (lane>>4)*4;
  #define DOG(G, A0,A1,A2,A3) { \
    const int oc0g = ocb + G*16 + ocl; \
    float bj0=bias[oc0g], bj1=bias[oc0g+1], bj2=bias[oc0g+2], bj3=bias[oc0g+3]; \
    float v00=A0[0]+bj0, v01=A0[1]+bj1, v02=A0[2]+bj2, v03=A0[3]+bj3; \
    float v10=A1[0]+bj0, v11=A1[1]+bj1, v12=A1[2]+bj2, v13=A1[3]+bj3; \
    float v20=A2[0]+bj0, v21=A2[1]+bj1, v22=A2[2]+bj2, v23=A2[3]+bj3; \
    float v30=A3[0]+bj0, v31=A3[1]+bj1, v32=A3[2]+bj2, v33=A3[3]+bj3; \
    float s0=v00+v10+v20+v30, q0=v00*v00+v10*v10+v20*v20+v30*v30; \
    float s1=v01+v11+v21+v31, q1=v01*v01+v11*v11+v21*v21+v31*v31; \
    float s2=v02+v12+v22+v32, q2=v02*v02+v12*v12+v22*v22+v32*v32; \
    float s3=v03+v13+v23+v33, q3=v03*v03+v13*v13+v23*v23+v33*v33; \
    s0+=__shfl_xor(s0,1,64); s0+=__shfl_xor(s0,2,64); s0+=__shfl_xor(s0,4,64); s0+=__shfl_xor(s0,8,64); \
    q0+=__shfl_xor(q0,1,64); q0+=__shfl_xor(q0,2,64); q0+=__shfl_xor(q0,4,64); q0+=__shfl_xor(q0,8,64); \
    s1+=__shfl_xor(s1,1,64); s1+=__shfl_xor(s1,2,64); s1+=__shfl_xor(s1,4,64); s1+=__shfl_xor(s1,8,64); \
    q1+=__shfl_xor(q1,1,64); q1+=__shfl_xor(q1,2,64); q1+=__shfl_xor(q1,4,64); q1+=__shfl_xor(q1,8,64); \
    s2+=__shfl_xor(s2,1,64); s2+=__shfl_xor(s2,2,64); s2+=__shfl_xor(s2,4,64); s2+=__shfl_xor(s2,8,64); \
    q2+=__shfl_xor(q2,1,64); q2+=__shfl_xor(q2,2,64); q2+=__shfl_xor(q2,4,64); q2+=__shfl_xor(q2,8,64); \
    s3+=__shfl_xor(s3,1,64); s3+=__shfl_xor(s3,2,64); s3+=__shfl_xor(s3,4,64); s3+=__shfl_xor(s3,8,64); \
    q3+=__shfl_xor(q3,1,64); q3+=__shfl_xor(q3,2,64); q3+=__shfl_xor(q3,4,64); q3+=__shfl_xor(q3,8,64); \
    if (colx==0){ \
      atomicAdd(&ss[oc0g],s0);   atomicAdd(&sq[oc0g],q0); \
      atomicAdd(&ss[oc0g+1],s1); atomicAdd(&sq[oc0g+1],q1); \
      atomicAdd(&ss[oc0g+2],s2); atomicAdd(&sq[oc0g+2],q2); \
      atomicAdd(&ss[oc0g+3],s3); atomicAdd(&sq[oc0g+3],q3); \
    } \
    if (outh){ \
      size_t pb = (size_t)((b<<16) + tX + colx); \
      *(short4*)&outh[(pb + ((tY+ry+0)<<8))*64 + oc0g] = make_short4(to_bf16(v00),to_bf16(v01),to_bf16(v02),to_bf16(v03)); \
      *(short4*)&outh[(pb + ((tY+ry+1)<<8))*64 + oc0g] = make_short4(to_bf16(v10),to_bf16(v11),to_bf16(v12),to_bf16(v13)); \
      *(short4*)&outh[(pb + ((tY+ry+2)<<8))*64 + oc0g] = make_short4(to_bf16(v20),to_bf16(v21),to_bf16(v22),to_bf16(v23)); \
      *(short4*)&outh[(pb + ((tY+ry+3)<<8))*64 + oc0g] = make_short4(to_bf16(v30),to_bf16(v31),to_bf16(v32),to_bf16(v33)); \
    } else { \
      size_t cb0 = (((size_t)(b*64+oc0g))<<16) + ((tY+ry)<<8) + tX + colx; \
      outf[cb0          ] = v00; outf[cb0+(1<<16)      ] = v01; outf[cb0+(2<<16)      ] = v02; outf[cb0+(3<<16)      ] = v03; \
      outf[cb0+256      ] = v10; outf[cb0+(1<<16)+256  ] = v11; outf[cb0+(2<<16)+256  ] = v12; outf[cb0+(3<<16)+256  ] = v13; \
      outf[cb0+512      ] = v20; outf[cb0+(1<<16)+512  ] = v21; outf[cb0+(2<<16)+512  ] = v22; outf[cb0+(3<<16)+512  ] = v23; \
      outf[cb0+768      ] = v30; outf[cb0+(1<<16)+768  ] = v31; outf[cb0+(2<<16)+768  ] = v32; outf[cb0+(3<<16)+768  ] = v33; \
    } \
  }
  DOG(0, a00,a01,a02,a03)
  DOG(1, a10,a11,a12,a13)
  #undef DOG
  __syncthreads();
  if (t < 64){
    atomicAdd(&stat[t],    ss[t]);
    atomicAdd(&stat[64+t], sq[t]);
  }
}

// bn_fin fused: computes sc/sh from raw stats in LDS, then applies BN+relu.
__global__ __launch_bounds__(256) void bn_apply(float* __restrict__ x, const float* __restrict__ bnst,
                                                const float* __restrict__ g, const float* __restrict__ be){
  __shared__ float sBN[128];
  if (threadIdx.x < 64){
    int c = threadIdx.x;
    const float n = 131072.f;
    float m = bnst[c]/n;
    float v = fmaxf(bnst[64+c]/n - m*m, 0.f);
    float sc = g[c]*rsqrtf(v+1e-5f);
    sBN[c]=sc; sBN[64+c]=be[c]-m*sc;
  }
  __syncthreads();
  size_t idx = (size_t)blockIdx.x*256 + threadIdx.x;
  size_t stride = (size_t)gridDim.x*256;
  float4* p = (float4*)x;
  for (size_t k=idx; k<2097152ULL; k+=stride){
    int c = (int)((k>>14)&63);
    float sc = sBN[c], sh = sBN[64+c];
    float4 v = p[k];
    v.x=fmaxf(v.x*sc+sh,0.f); v.y=fmaxf(v.y*sc+sh,0.f);
    v.z=fmaxf(v.z*sc+sh,0.f); v.w=fmaxf(v.w*sc+sh,0.f);
    p[k]=v;
  }
}

// ---------------- launch ----------------
extern "C" void kernel_launch(void* const* d_in, const int* in_sizes, int n_in,
                              void* d_out, int out_size, void* d_ws, size_t ws_size,
                              hipStream_t stream){
  const float* pts  = (const float*)d_in[0];
  const void*  mask = d_in[1];
  const float* w1 = (const float*)d_in[2];
  const float* b1 = (const float*)d_in[3];
  const float* g1 = (const float*)d_in[4];
  const float* be1= (const float*)d_in[5];
  const float* w2 = (const float*)d_in[6];
  const float* b2 = (const float*)d_in[7];
  const float* g2 = (const float*)d_in[8];
  const float* be2= (const float*)d_in[9];
  const float* cw[3]  = {(const float*)d_in[10],(const float*)d_in[14],(const float*)d_in[18]};
  const float* cb[3]  = {(const float*)d_in[11],(const float*)d_in[15],(const float*)d_in[19]};
  const float* cg[3]  = {(const float*)d_in[12],(const float*)d_in[16],(const float*)d_in[20]};
  const float* cbe[3] = {(const float*)d_in[13],(const float*)d_in[17],(const float*)d_in[21]};
  float* out = (float*)d_out;

  char* W = (char*)d_ws;
  size_t off = 0;
  auto A = [&](size_t n){ size_t r = off; off = (off + n + 255) & ~(size_t)255; return r; };
  short*    BIGH  = (short*)   (W + A((size_t)2*NCELL*64*2));
  short*    OUT1H = (short*)   (W + A((size_t)2*NCELL*64*2));
  int*      PID   = (int*)     (W + A((size_t)2*NPTS*4));
  int*      CRANK = (int*)     (W + A((size_t)2*NCELL*4));
  int*      CSTART= (int*)     (W + A((size_t)2*NCELL*4));
  int*      PLIST = (int*)     (W + A((size_t)2*NPTS*4));
  int*      PCELL = (int*)     (W + A((size_t)2*MAXP*4));
  float*    CPTS  = (float*)   (W + A((size_t)2*NPTS*12*4));
  float*    TBUF  = (float*)   (W + A((size_t)2*NPTS*64*4));
  unsigned* FMN   = (unsigned*)(W + A((size_t)2*MAXP*64*4));
  short*    WH    = (short*)   (W + A((size_t)3*36864*2));
  short*    W1H   = (short*)   (W + A((size_t)2048*2));
  short*    W2H   = (short*)   (W + A((size_t)4096*2));
  int2*     BPART = (int2*)    (W + A((size_t)2*64*8));
  // ---- zero block ----
  size_t zbeg = off;
  unsigned* FMX   = (unsigned*)(W + A((size_t)2*MAXP*64*4));
  int*      CCNT  = (int*)     (W + A((size_t)2*NCELL*4));
  int*      CTMP  = (int*)     (W + A((size_t)2*NCELL*4));
  float*    PSUM  = (float*)   (W + A((size_t)2*MAXP*16));
  float*    LSTAT = (float*)   (W + A((size_t)16*2*65*4));
  float*    L2STAT= (float*)   (W + A((size_t)16*2*2*64*4));
  float*    BNST  = (float*)   (W + A((size_t)3*256*4));
  int*      HEAVY = (int*)     (W + A((size_t)(2+2*64)*4));
  int*      MISC  = (int*)     (W + A(256));
  size_t zend = off;

  prep<<<2048,256,0,stream>>>((uint4*)BIGH, (size_t)2*NCELL*64*2/16,
                              (uint4*)(W+zbeg), (zend-zbeg)/16,
                              cw[0], cw[1], cw[2], WH, w1, w2, W1H, W2H,
                              (uint4*)FMN, (size_t)2*MAXP*64*4/16);

  dim3 perPt((NPTS+255)/256, 2);

  compute_pid<<<perPt,256,0,stream>>>(pts, mask, PID, CCNT);
  scan_a<<<dim3(64,2),256,0,stream>>>(CCNT, BPART);
  scan_b<<<dim3(64,2),256,0,stream>>>(CCNT, BPART, CRANK, CSTART, PCELL, MISC, HEAVY);
  scatter_cpts<<<perPt,256,0,stream>>>(pts, PID, CCNT, CRANK, CSTART, CTMP, PLIST, CPTS, PSUM);
  heavy_select<<<dim3(64,2),64,0,stream>>>(pts, CCNT, CRANK, CSTART, PLIST, HEAVY, CPTS, PSUM);
  moments<<<dim3(120,2),256,0,stream>>>(CPTS, PSUM, MISC, LSTAT);
  point_mlp<<<dim3(256,2),256,0,stream>>>(CPTS, MISC, w1, b1, g1, be1,
                                          W1H, W2H, LSTAT, TBUF);
  seg_max<<<dim3(938,2),256,0,stream>>>(TBUF, CPTS, MISC, L2STAT, FMX, FMN);
  scatter_bev<<<dim3(512,2),256,0,stream>>>(w1, b1, g1, be1, w2, b2, g2, be2,
                                            LSTAT, L2STAT, FMX, FMN, PCELL, MISC, BIGH);

  // conv1: BIGH -> OUT1H (bf16, raw) + stats BNST0
  conv_mfma<<<dim3(16,16,2),512,0,stream>>>(BIGH, WH, cb[0], nullptr, nullptr, nullptr,
                                            OUT1H, nullptr, BNST);
  // conv2: OUT1H (bn1+relu in-kernel from BNST0) -> BIGH + stats BNST1
  conv_mfma<<<dim3(16,16,2),512,0,stream>>>(OUT1H, WH+36864, cb[1], BNST, cg[0], cbe[0],
                                            BIGH, nullptr, BNST+256);
  // conv3: BIGH (bn2+relu from BNST1) -> d_out (fp32) + stats BNST2
  conv_mfma<<<dim3(16,16,2),512,0,stream>>>(BIGH, WH+2*36864, cb[2], BNST+256, cg[1], cbe[1],
                                            nullptr, out, BNST+512);
  bn_apply<<<2048,256,0,stream>>>(out, BNST+512, cg[2], cbe[2]);
}

// Round 19
// 215.232 us; speedup vs baseline: 1.0530x; 1.0047x over previous
//
#include <hip/hip_runtime.h>

#define NPTS 60000
#define NXG 256
#define NCELL 65536
#define MAXP 12000
#define MAXPP 32
#define NROWS (MAXP*MAXPP)

typedef float f32x32 __attribute__((ext_vector_type(32)));
typedef float f32x4  __attribute__((ext_vector_type(4)));
typedef short s16x8  __attribute__((ext_vector_type(8)));

__device__ __forceinline__ short to_bf16(float f){
  unsigned u = __float_as_uint(f);
  unsigned r = (u + 0x7FFFu + ((u>>16)&1u)) >> 16;
  return (short)r;
}
// order-preserving float<->uint for atomicMax/Min
__device__ __forceinline__ unsigned mapf(float f){
  unsigned u = __float_as_uint(f);
  return (u & 0x80000000u) ? ~u : (u | 0x80000000u);
}
__device__ __forceinline__ float unmapf(unsigned u){
  unsigned b = (u & 0x80000000u) ? (u ^ 0x80000000u) : ~u;
  return __uint_as_float(b);
}

// ---------------- prep: zero ws + conv/mlp weights bf16 + FMN pattern ----------------
__global__ __launch_bounds__(256) void prep(uint4* __restrict__ p1, size_t n1,
                                            uint4* __restrict__ p2, size_t n2,
                                            const float* __restrict__ w0, const float* __restrict__ w1,
                                            const float* __restrict__ w2, short* __restrict__ wh,
                                            const float* __restrict__ mw1, const float* __restrict__ mw2,
                                            short* __restrict__ w1h, short* __restrict__ w2h,
                                            uint4* __restrict__ fmn, size_t nfmn){
  size_t idx = (size_t)blockIdx.x*256 + threadIdx.x;
  size_t stride = (size_t)gridDim.x*256;
  const uint4 z = make_uint4(0,0,0,0);
  const uint4 ff = make_uint4(0xFFFFFFFFu,0xFFFFFFFFu,0xFFFFFFFFu,0xFFFFFFFFu);
  for (size_t k=idx; k<n1; k+=stride) p1[k]=z;
  for (size_t k=idx; k<n2; k+=stride) p2[k]=z;
  for (size_t k=idx; k<nfmn; k+=stride) fmn[k]=ff;
  for (size_t k=idx; k<3*36864; k+=stride){
    int l = (int)(k / 36864), r = (int)(k - (size_t)l*36864);
    const float* w = (l==0)? w0 : ((l==1)? w1 : w2);
    int ic = r & 63, oc = (r>>6)&63, tap = r>>12;
    wh[k] = to_bf16(w[(oc*64+ic)*9 + tap]);
  }
  for (size_t k=idx; k<2048; k+=stride){           // w1h: [k(32, zero-pad>=10)][oc]
    int kk = (int)(k>>6), oc = (int)(k&63);
    w1h[k] = (kk<10) ? to_bf16(mw1[kk*64+oc]) : (short)0;
  }
  for (size_t k=idx; k<4096; k+=stride)            // w2h: [k(64)][oc]
    w2h[k] = to_bf16(mw2[k]);
}

// ---------------- pillarize (mask dtype probed per-block) ----------------
__global__ void compute_pid(const float* __restrict__ pts, const void* __restrict__ maskp,
                            int* __restrict__ pid, int* __restrict__ ccnt){
  __shared__ int cf32, cbig;
  if (threadIdx.x==0){ cf32=0; cbig=0; }
  __syncthreads();
  {
    int lf=0, lb=0;
    const unsigned* mu = (const unsigned*)maskp;
    for (int k=0;k<4;k++){
      unsigned x = mu[threadIdx.x*4+k];
      if (x==0x3f800000u) lf++;
      else if (x>1u) lb++;
    }
    if (lf) atomicAdd(&cf32, lf);
    if (lb) atomicAdd(&cbig, lb);
  }
  __syncthreads();
  int mode = (cf32>64) ? 2 : ((cbig>0) ? 1 : 0);
  int i = blockIdx.x*blockDim.x + threadIdx.x;
  if (i>=NPTS) return;
  int b = blockIdx.y;
  int gi = b*NPTS+i;
  bool m;
  if (mode==0)      m = ((const int*)maskp)[gi]!=0;
  else if (mode==1) m = ((const unsigned char*)maskp)[gi]!=0;
  else              m = ((const float*)maskp)[gi]!=0.f;
  int cell = -1;
  if (m){
    float x = pts[(size_t)gi*5+0], y = pts[(size_t)gi*5+1];
    int ix = (int)((x - (-32.0f)) / 0.25f);
    ix = ix<0?0:(ix>255?255:ix);
    int iy = (int)((y - (-32.0f)) / 0.25f);
    iy = iy<0?0:(iy>255?255:iy);
    cell = iy*NXG + ix;
    atomicAdd(&ccnt[b*NCELL+cell], 1);
  }
  pid[gi] = cell;
}

// ---------------- parallel occupancy scan ----------------
__global__ __launch_bounds__(256) void scan_a(const int* __restrict__ ccnt,
                                              int2* __restrict__ bpart){
  int b = blockIdx.y, blk = blockIdx.x, t = threadIdx.x;
  int4 v = *(const int4*)&ccnt[b*NCELL + blk*1024 + t*4];
  int occ = (v.x>0)+(v.y>0)+(v.z>0)+(v.w>0);
  int cnt = v.x+v.y+v.z+v.w;
  #pragma unroll
  for (int off=32; off>0; off>>=1){
    occ += __shfl_xor(occ, off, 64);
    cnt += __shfl_xor(cnt, off, 64);
  }
  __shared__ int so[4], sc[4];
  int wv = t>>6, lane = t&63;
  if (lane==0){ so[wv]=occ; sc[wv]=cnt; }
  __syncthreads();
  if (t==0) bpart[b*64+blk] = make_int2(so[0]+so[1]+so[2]+so[3], sc[0]+sc[1]+sc[2]+sc[3]);
}

__global__ __launch_bounds__(256) void scan_b(const int* __restrict__ ccnt,
    const int2* __restrict__ bpart,
    int* __restrict__ crank, int* __restrict__ cstart, int* __restrict__ pcell,
    int* __restrict__ misc, int* __restrict__ heavy){
  __shared__ int swo[4], swc[4], sk[4];
  __shared__ int bo_, bc_;
  int b = blockIdx.y, blk = blockIdx.x, t = threadIdx.x;
  int wv = t>>6, lane = t&63;
  if (t < 64){
    int2 p = bpart[b*64+t];
    int po = (t<blk)? p.x : 0;
    int pc = (t<blk)? p.y : 0;
    int to = p.x;
    int tc = p.y;
    #pragma unroll
    for (int off=32; off>0; off>>=1){
      po += __shfl_xor(po, off, 64);
      pc += __shfl_xor(pc, off, 64);
      to += __shfl_xor(to, off, 64);
      tc += __shfl_xor(tc, off, 64);
    }
    if (t==0){
      bo_ = po; bc_ = pc;
      if (blk==0){
        misc[1+b] = (to < MAXP) ? to : MAXP;
        misc[5+b] = tc;               // total masked points
      }
    }
  }
  int4 v = *(const int4*)&ccnt[b*NCELL + blk*1024 + t*4];
  int occ = (v.x>0)+(v.y>0)+(v.z>0)+(v.w>0);
  int cnt = v.x+v.y+v.z+v.w;
  int io = occ, ic = cnt;
  #pragma unroll
  for (int off=1; off<64; off<<=1){
    int ao = __shfl_up(io, off, 64);
    int ac = __shfl_up(ic, off, 64);
    if (lane >= off){ io += ao; ic += ac; }
  }
  if (lane==63){ swo[wv]=io; swc[wv]=ic; }
  __syncthreads();
  int wvo=0, wvc=0;
  #pragma unroll
  for (int w2=0; w2<4; w2++){
    if (w2<wv){ wvo += swo[w2]; wvc += swc[w2]; }
  }
  int eo = bo_ + wvo + io - occ;
  int ec = bc_ + wvc + ic - cnt;
  int kept = 0;
  int cellb = blk*1024 + t*4;
  int vv[4] = {v.x,v.y,v.z,v.w};
  #pragma unroll
  for (int j=0;j<4;j++){
    int c = cellb+j; int val = vv[j];
    if (val>0){
      crank[b*NCELL+c]=eo; cstart[b*NCELL+c]=ec;
      if (eo<MAXP){
        pcell[b*MAXP+eo]=c;
        kept += (val<MAXPP)? val : MAXPP;
        if (val>MAXPP){
          int hi = atomicAdd(&heavy[b],1);
          if (hi<64) heavy[2 + b*64 + hi] = c;
        }
      }
      eo++; ec+=val;
    }
  }
  #pragma unroll
  for (int off=32; off>0; off>>=1) kept += __shfl_xor(kept, off, 64);
  if (lane==0) sk[wv]=kept;
  __syncthreads();
  if (t==0) atomicAdd(&misc[3+b], sk[0]+sk[1]+sk[2]+sk[3]);
}

// ---------------- scatter: write CPTS directly at pillar-sorted position ----------------
// CPTS[pos]: [x,y,z,i1][i2,gx,gy,rid][dx,dy,dz,0]  (quad2 filled by moments)
__global__ void scatter_cpts(const float* __restrict__ pts, const int* __restrict__ pid,
    const int* __restrict__ ccnt, const int* __restrict__ crank, const int* __restrict__ cstart,
    int* __restrict__ ctmp, int* __restrict__ plist,
    float* __restrict__ cpts, float* __restrict__ psum){
  int i = blockIdx.x*blockDim.x + threadIdx.x;
  if (i>=NPTS) return;
  int b = blockIdx.y;
  int gi = b*NPTS+i;
  int cell = pid[gi];
  if (cell<0) return;
  int bc = b*NCELL+cell;
  int pos = cstart[bc] + atomicAdd(&ctmp[bc],1);
  plist[b*NPTS+pos] = i;
  int cnt = ccnt[bc], r = crank[bc];
  int rid = (r<MAXP && cnt<=MAXPP) ? r : -1;
  const float* qp = &pts[(size_t)gi*5];
  float x=qp[0], y=qp[1], z=qp[2], i1=qp[3], i2=qp[4];
  float gx = -32.0f + ((float)(cell&255)+0.5f)*0.25f;
  float gy = -32.0f + ((float)(cell>>8)+0.5f)*0.25f;
  float4* cp = (float4*)&cpts[(size_t)(b*NPTS+pos)*12];
  cp[0] = make_float4(x,y,z,i1);
  cp[1] = make_float4(i2,gx,gy,__int_as_float(rid));
  if (rid>=0){
    float* s = &psum[(size_t)(b*MAXP+rid)*4];
    atomicAdd(s+0,x); atomicAdd(s+1,y); atomicAdd(s+2,z); atomicAdd(s+3,1.f);
  }
}

// heavy cells (>32 pts): select first-32-by-original-index, patch CPTS rid + psum
__global__ void heavy_select(const float* __restrict__ pts,
    const int* __restrict__ ccnt, const int* __restrict__ crank,
    const int* __restrict__ cstart, const int* __restrict__ plist,
    const int* __restrict__ heavy, float* __restrict__ cpts, float* __restrict__ psum){
  int b = blockIdx.y;
  int hn = heavy[b]; if (hn>64) hn=64;
  if ((int)blockIdx.x >= hn) return;
  int cell = heavy[2 + b*64 + blockIdx.x];
  int bc = b*NCELL+cell;
  int cnt = ccnt[bc], start = cstart[bc], pr = crank[bc];
  for (int e=threadIdx.x; e<cnt; e+=blockDim.x){
    int pe = plist[b*NPTS+start+e];
    int rank=0;
    for (int k=0;k<cnt;k++) rank += (plist[b*NPTS+start+k] < pe);
    if (rank<MAXPP && pr<MAXP){
      cpts[(size_t)(b*NPTS+start+e)*12 + 7] = __int_as_float(pr);
      const float* qp = &pts[(size_t)(b*NPTS+pe)*5];
      float* s = &psum[(size_t)(b*MAXP+pr)*4];
      atomicAdd(s+0,qp[0]); atomicAdd(s+1,qp[1]); atomicAdd(s+2,qp[2]); atomicAdd(s+3,1.f);
    }
  }
}

// ---------------- global aug moments (65 register accumulators) + centroid writeback ----
#define MM_ACC(K,V) { if ((K)<32) m0[(K)&31]+=(V); else if ((K)<64) m1[((K)-32)&31]+=(V); else m2+=(V); }
__global__ __launch_bounds__(256) void moments(float* __restrict__ cpts,
    const float* __restrict__ psum, const int* __restrict__ misc,
    float* __restrict__ lstat){
  int b = blockIdx.y;
  int n = misc[5+b];
  f32x32 m0, m1; float m2 = 0.f;
  #pragma unroll
  for (int j=0;j<32;j++){ m0[j]=0.f; m1[j]=0.f; }
  for (int pos = blockIdx.x*256+threadIdx.x; pos<n; pos += gridDim.x*256){
    float4* cp = (float4*)&cpts[(size_t)(b*NPTS+pos)*12];
    float4 f1 = cp[0], f2 = cp[1];
    int rid = __float_as_int(f2.w);
    if (rid<0) continue;
    float4 mc = *(const float4*)&psum[(size_t)(b*MAXP+rid)*4];
    float inv = 1.f/fmaxf(mc.w,1.f);
    float dx = f1.x-mc.x*inv, dy = f1.y-mc.y*inv, dz = f1.z-mc.z*inv;
    cp[2] = make_float4(dx,dy,dz,0.f);
    float aug[10] = {f1.x,f1.y,f1.z,f1.w,f2.x, dx,dy,dz, f2.y,f2.z};
    #pragma unroll
    for (int d=0; d<10; d++){
      #pragma unroll
      for (int e=d; e<10; e++){
        const int k = d*10 - d*(d-1)/2 + (e-d);
        MM_ACC(k, aug[d]*aug[e]);
      }
      const int kl = 55+d;
      MM_ACC(kl, aug[d]);
    }
  }
  int lane = threadIdx.x & 63;
  int rep = ((blockIdx.x*256+threadIdx.x)>>6) & 15;
  float* dst = &lstat[(size_t)(rep*2+b)*65];
  #pragma unroll
  for (int j=0;j<32;j++){
    float v = m0[j];
    #pragma unroll
    for (int off=32; off>0; off>>=1) v += __shfl_xor(v, off, 64);
    if (lane==0) atomicAdd(&dst[j], v);
  }
  #pragma unroll
  for (int j=0;j<32;j++){
    float v = m1[j];
    #pragma unroll
    for (int off=32; off>0; off>>=1) v += __shfl_xor(v, off, 64);
    if (lane==0) atomicAdd(&dst[32+j], v);
  }
  {
    float v = m2;
    #pragma unroll
    for (int off=32; off>0; off>>=1) v += __shfl_xor(v, off, 64);
    if (lane==0) atomicAdd(&dst[64], v);
  }
}

// ---------------- point-parallel MLP via MFMA: T[pos][64] = relu(bn1(Aug@W1))@W2 ----------
#define MFMA16(A,B,C) __builtin_amdgcn_mfma_f32_16x16x32_bf16(A,B,C,0,0,0)

__global__ __launch_bounds__(256) void point_mlp(const float* __restrict__ cpts,
    const int* __restrict__ misc,
    const float* __restrict__ w1, const float* __restrict__ b1,
    const float* __restrict__ g1, const float* __restrict__ be1,
    const short* __restrict__ w1h, const short* __restrict__ w2h,
    const float* __restrict__ lstat, float* __restrict__ tbuf){
  __shared__ float sM[65];
  __shared__ float sBN1[128];
  __shared__ short zT[4][16*72];
  const int b = blockIdx.y;
  const int t = threadIdx.x;
  for (int e=t; e<65; e+=256){
    float s=0.f;
    for (int r=0;r<16;r++) s += lstat[(size_t)(r*2+b)*65+e];
    sM[e]=s;
  }
  __syncthreads();
  if (t < 64){
    int c = t;
    float wcol[10];
    #pragma unroll
    for (int d=0;d<10;d++) wcol[d] = w1[d*64+c];
    float b1c = b1[c];
    float nk = (float)misc[3+b];
    const float N = (float)NROWS;
    float pad = N - nk;
    float lw = 0.f;
    #pragma unroll
    for (int d=0;d<10;d++) lw += sM[55+d]*wcol[d];
    float s = nk*b1c + lw;
    float qq = nk*b1c*b1c + 2.f*b1c*lw;
    #pragma unroll
    for (int d=0; d<10; d++){
      #pragma unroll
      for (int e=d; e<10; e++){
        float m = sM[d*10 - d*(d-1)/2 + (e-d)];
        qq += ((d==e)?1.f:2.f)*m*wcol[d]*wcol[e];
      }
    }
    float St = s + pad*b1c;
    float Qt = qq + pad*b1c*b1c;
    float mu = St/N;
    float var = fmaxf(Qt/N - mu*mu, 0.f);
    float sc = g1[c]*rsqrtf(var+1e-5f);
    float sh = be1[c]-mu*sc;
    sBN1[c]=sc; sBN1[64+c]=b1c*sc+sh;   // z = relu(y*sc + (b1*sc+sh)), y excludes b1
  }
  __syncthreads();
  const int lane = t & 63, wv = t >> 6;
  const int colx = lane & 15;
  const int kq = lane >> 4, kb = kq*8;
  s16x8 w1f0, w1f1, w1f2, w1f3;
  s16x8 a2f0, a2f1, a2f2, a2f3;
  s16x8 b2f0, b2f1, b2f2, b2f3;
  #pragma unroll
  for (int j=0;j<8;j++){
    w1f0[j]=w1h[(kb+j)*64 +  0+colx]; w1f1[j]=w1h[(kb+j)*64 + 16+colx];
    w1f2[j]=w1h[(kb+j)*64 + 32+colx]; w1f3[j]=w1h[(kb+j)*64 + 48+colx];
    a2f0[j]=w2h[(kb+j)*64 +  0+colx]; a2f1[j]=w2h[(kb+j)*64 + 16+colx];
    a2f2[j]=w2h[(kb+j)*64 + 32+colx]; a2f3[j]=w2h[(kb+j)*64 + 48+colx];
    b2f0[j]=w2h[(32+kb+j)*64 +  0+colx]; b2f1[j]=w2h[(32+kb+j)*64 + 16+colx];
    b2f2[j]=w2h[(32+kb+j)*64 + 32+colx]; b2f3[j]=w2h[(32+kb+j)*64 + 48+colx];
  }
  float sc1v0=sBN1[colx],    sh1v0=sBN1[64+colx];
  float sc1v1=sBN1[16+colx], sh1v1=sBN1[80+colx];
  float sc1v2=sBN1[32+colx], sh1v2=sBN1[96+colx];
  float sc1v3=sBN1[48+colx], sh1v3=sBN1[112+colx];
  const int n = misc[5+b];
  const int ntiles = (n+15)>>4;
  short* myZ = zT[wv];
  for (int tile = blockIdx.x*4 + wv; tile < ntiles; tile += gridDim.x*4){
    int pos0 = tile*16;
    int pos = pos0 + colx;
    float aug[10];
    #pragma unroll
    for (int d=0;d<10;d++) aug[d]=0.f;
    if (pos < n){
      const float4* cp = (const float4*)&cpts[(size_t)(b*NPTS+pos)*12];
      float4 f1 = cp[0], f2 = cp[1], f3 = cp[2];
      aug[0]=f1.x; aug[1]=f1.y; aug[2]=f1.z; aug[3]=f1.w; aug[4]=f2.x;
      aug[5]=f3.x; aug[6]=f3.y; aug[7]=f3.z;
      aug[8]=f2.y; aug[9]=f2.z;
    }
    s16x8 af;
    #pragma unroll
    for (int j=0;j<8;j++){
      float v = 0.f;
      if (kq==0) v = aug[j];
      else if (kq==1 && j<2) v = aug[8+j];
      af[j] = to_bf16(v);
    }
    f32x4 y0={0.f,0.f,0.f,0.f}, y1=y0, y2=y0, y3=y0;
    y0 = MFMA16(af, w1f0, y0);
    y1 = MFMA16(af, w1f1, y1);
    y2 = MFMA16(af, w1f2, y2);
    y3 = MFMA16(af, w1f3, y3);
    #pragma unroll
    for (int m=0;m<4;m++){
      int pr = (kq*4+m)*72;
      myZ[pr +  0+colx] = to_bf16(fmaxf(y0[m]*sc1v0+sh1v0, 0.f));
      myZ[pr + 16+colx] = to_bf16(fmaxf(y1[m]*sc1v1+sh1v1, 0.f));
      myZ[pr + 32+colx] = to_bf16(fmaxf(y2[m]*sc1v2+sh1v2, 0.f));
      myZ[pr + 48+colx] = to_bf16(fmaxf(y3[m]*sc1v3+sh1v3, 0.f));
    }
    s16x8 az0 = *(const s16x8*)&myZ[colx*72 + kb];
    s16x8 az1 = *(const s16x8*)&myZ[colx*72 + 32 + kb];
    f32x4 t0={0.f,0.f,0.f,0.f}, t1=t0, t2=t0, t3=t0;
    t0 = MFMA16(az0, a2f0, t0); t0 = MFMA16(az1, b2f0, t0);
    t1 = MFMA16(az0, a2f1, t1); t1 = MFMA16(az1, b2f1, t1);
    t2 = MFMA16(az0, a2f2, t2); t2 = MFMA16(az1, b2f2, t2);
    t3 = MFMA16(az0, a2f3, t3); t3 = MFMA16(az1, b2f3, t3);
    #pragma unroll
    for (int m=0;m<4;m++){
      int pm = pos0 + kq*4 + m;
      if (pm < n){
        float* dst = &tbuf[(size_t)(b*NPTS+pm)*64];
        dst[ 0+colx] = t0[m];
        dst[16+colx] = t1[m];
        dst[32+colx] = t2[m];
        dst[48+colx] = t3[m];
      }
    }
  }
}

// ---------------- segmented max/min over T (coalesced, atomic flush) ----------------
__global__ __launch_bounds__(256) void seg_max(const float* __restrict__ tbuf,
    const float* __restrict__ cpts, const int* __restrict__ misc,
    float* __restrict__ l2stat, unsigned* __restrict__ fmxU, unsigned* __restrict__ fmnU){
  const int b = blockIdx.y;
  const int lane = threadIdx.x & 63;
  const int n = misc[5+b];
  const int w = blockIdx.x*4 + (threadIdx.x>>6);
  float s2 = 0.f, q2 = 0.f;
  int p0 = w*16;
  if (p0 < n){
    int p1 = p0+16; if (p1>n) p1=n;
    int cur = -1;
    float tmax = -1e30f, tmin = 1e30f;
    for (int pos=p0; pos<p1; ++pos){
      int rid = __float_as_int(cpts[(size_t)(b*NPTS+pos)*12 + 7]);
      float tv = tbuf[(size_t)(b*NPTS+pos)*64 + lane];
      if (rid >= 0){
        if (rid != cur){
          if (cur >= 0){
            atomicMax(&fmxU[(size_t)(b*MAXP+cur)*64 + lane], mapf(tmax));
            atomicMin(&fmnU[(size_t)(b*MAXP+cur)*64 + lane], mapf(tmin));
          }
          cur = rid; tmax = -1e30f; tmin = 1e30f;
        }
        tmax = fmaxf(tmax, tv);
        tmin = fminf(tmin, tv);
        s2 += tv; q2 += tv*tv;
      }
    }
    if (cur >= 0){
      atomicMax(&fmxU[(size_t)(b*MAXP+cur)*64 + lane], mapf(tmax));
      atomicMin(&fmnU[(size_t)(b*MAXP+cur)*64 + lane], mapf(tmin));
    }
  }
  int rep = w & 15;
  atomicAdd(&l2stat[(size_t)((rep*2+b)*2+0)*64+lane], s2);
  atomicAdd(&l2stat[(size_t)((rep*2+b)*2+1)*64+lane], q2);
}

// ---------------- BN2 params (in-block) + BN2+relu on pillar max/min -> bf16 BEV ----------
__global__ __launch_bounds__(256) void scatter_bev(
    const float* __restrict__ w1, const float* __restrict__ b1,
    const float* __restrict__ g1, const float* __restrict__ be1,
    const float* __restrict__ w2, const float* __restrict__ b2,
    const float* __restrict__ g2, const float* __restrict__ be2,
    const float* __restrict__ lstat, const float* __restrict__ l2stat,
    const unsigned* __restrict__ fmxU, const unsigned* __restrict__ fmnU,
    const int* __restrict__ pcell, const int* __restrict__ misc,
    short* __restrict__ bevh){
  __shared__ float M[65];
  __shared__ float z0s[64];
  __shared__ float sBN2[128];
  const int b = blockIdx.y;
  for (int e=threadIdx.x; e<65; e+=256){
    float s=0.f;
    for (int r=0;r<16;r++) s += lstat[(size_t)(r*2+b)*65+e];
    M[e]=s;
  }
  __syncthreads();
  if (threadIdx.x < 64){
    int c = threadIdx.x;
    float wcol[10];
    #pragma unroll
    for (int d=0;d<10;d++) wcol[d] = w1[d*64+c];
    float b1c = b1[c];
    float nk = (float)misc[3+b];
    const float N = (float)NROWS;
    float pad = N - nk;
    float lw = 0.f;
    #pragma unroll
    for (int d=0;d<10;d++) lw += M[55+d]*wcol[d];
    float s = nk*b1c + lw;
    float qq = nk*b1c*b1c + 2.f*b1c*lw;
    #pragma unroll
    for (int d=0; d<10; d++){
      #pragma unroll
      for (int e=d; e<10; e++){
        float m = M[d*10 - d*(d-1)/2 + (e-d)];
        qq += ((d==e)?1.f:2.f)*m*wcol[d]*wcol[e];
      }
    }
    float St = s + pad*b1c;
    float Qt = qq + pad*b1c*b1c;
    float mu = St/N;
    float var = fmaxf(Qt/N - mu*mu, 0.f);
    float sc1 = g1[c]*rsqrtf(var+1e-5f);
    float sh1 = be1[c]-mu*sc1;
    z0s[c] = fmaxf(b1c*sc1+sh1, 0.f);
  }
  __syncthreads();
  if (threadIdx.x < 64){
    int c = threadIdx.x;
    float nk = (float)misc[3+b];
    const float N = (float)NROWS;
    float pad = N - nk;
    float t0 = b2[c];
    for (int i2=0;i2<64;i2++) t0 += z0s[i2]*w2[(size_t)i2*64+c];
    float s2 = pad*t0, q2 = pad*t0*t0;
    for (int r=0;r<16;r++){
      s2 += l2stat[(size_t)((r*2+b)*2+0)*64+c];
      q2 += l2stat[(size_t)((r*2+b)*2+1)*64+c];
    }
    float m2 = s2/N;
    float v2 = fmaxf(q2/N - m2*m2, 0.f);
    float sc2 = g2[c]*rsqrtf(v2+1e-5f);
    sBN2[c]=sc2; sBN2[64+c]=be2[c]-m2*sc2;
  }
  __syncthreads();
  const int npil = misc[1+b];
  for (int tid = blockIdx.x*256+threadIdx.x; tid < 64*MAXP; tid += gridDim.x*256){
    int c = tid & 63;
    int p = tid >> 6;
    if (p >= npil) break;
    float sc2 = sBN2[c], sh2 = sBN2[64+c];
    size_t idx = (size_t)(b*MAXP+p)*64 + c;
    float tv = (sc2 >= 0.f) ? unmapf(fmxU[idx]) : unmapf(fmnU[idx]);
    float v = fmaxf(sc2*tv+sh2, 0.f);
    int cell = pcell[b*MAXP+p];
    bevh[((size_t)((b<<16) + cell))*64 + c] = to_bf16(v);
  }
}

// ---------------- fused MFMA conv3x3: one block per 16x16 tile, all 64 oc, 512 thr ----------
__global__ __launch_bounds__(512,4) void conv_mfma(const short* __restrict__ xh,
    const short* __restrict__ wh, const float* __restrict__ bias,
    const float* __restrict__ pstat, const float* __restrict__ pg, const float* __restrict__ pbe,
    short* __restrict__ outh, float* __restrict__ outf,
    float* __restrict__ stat){
  __shared__ short sX[324*40];
  __shared__ short sW[576*40];
  __shared__ float sBN[128];
  __shared__ float ss[64], sq[64];
  const int tX = blockIdx.x*16, tY = blockIdx.y*16;
  const int b = blockIdx.z;
  const int t = threadIdx.x;
  const int lane = t & 63, wv = t >> 6;
  const int colx = lane & 15;
  const int kb = (lane >> 4) * 8;
  const int ocb = (wv >> 2) * 32;
  const int ry  = (wv & 3) * 4;
  if (t < 64){ ss[t]=0.f; sq[t]=0.f; }
  if (t >= 64 && t < 128 && pstat){
    int c = t-64;
    const float n = 131072.f;
    float m = pstat[c]/n;
    float v = fmaxf(pstat[64+c]/n - m*m, 0.f);
    float sc = pg[c]*rsqrtf(v+1e-5f);
    sBN[c]=sc; sBN[64+c]=pbe[c]-m*sc;
  }

  f32x4 a00={0.f,0.f,0.f,0.f}, a01=a00, a02=a00, a03=a00;
  f32x4 a10=a00, a11=a00, a12=a00, a13=a00;

  for (int h=0; h<2; ++h){
    __syncthreads();
    for (int e=t; e<1296; e+=512){
      int px = e>>2, j = e&3;
      int yy = px/18, xx = px - yy*18;
      int gy = tY+yy-1, gx = tX+xx-1;
      uint4 v = make_uint4(0,0,0,0);
      if ((unsigned)gy<256u && (unsigned)gx<256u){
        v = *(const uint4*)&xh[((size_t)((b<<16) + (gy<<8) + gx))*64 + h*32 + j*8];
        if (pstat){
          unsigned arr[4] = {v.x, v.y, v.z, v.w};
          #pragma unroll
          for (int j2=0;j2<4;j2++){
            unsigned wrd = arr[j2];
            int ch = h*32 + j*8 + j2*2;
            float lo = __uint_as_float(wrd<<16);
            float hi = __uint_as_float(wrd & 0xffff0000u);
            lo = fmaxf(lo*sBN[ch]+sBN[64+ch], 0.f);
            hi = fmaxf(hi*sBN[ch+1]+sBN[64+ch+1], 0.f);
            arr[j2] = (unsigned)(unsigned short)to_bf16(lo) |
                      (((unsigned)(unsigned short)to_bf16(hi))<<16);
          }
          v = make_uint4(arr[0],arr[1],arr[2],arr[3]);
        }
      }
      *(uint4*)&sX[px*40 + j*8] = v;
    }
    for (int e=t; e<2304; e+=512){
      int row = e>>2, j = e&3;
      int tap = row>>6, oc = row&63;
      uint4 v = *(const uint4*)&wh[(size_t)tap*4096 + oc*64 + h*32 + j*8];
      *(uint4*)&sW[row*40 + j*8] = v;
    }
    __syncthreads();
    #pragma unroll
    for (int tap=0; tap<9; ++tap){
      const int dy = tap/3, dx = tap - dy*3;
      s16x8 wA = *(const s16x8*)&sW[(tap*64 + ocb +  0 + colx)*40 + kb];
      s16x8 wB = *(const s16x8*)&sW[(tap*64 + ocb + 16 + colx)*40 + kb];
      s16x8 x0 = *(const s16x8*)&sX[((ry+0+dy)*18 + colx+dx)*40 + kb];
      s16x8 x1 = *(const s16x8*)&sX[((ry+1+dy)*18 + colx+dx)*40 + kb];
      s16x8 x2 = *(const s16x8*)&sX[((ry+2+dy)*18 + colx+dx)*40 + kb];
      s16x8 x3 = *(const s16x8*)&sX[((ry+3+dy)*18 + colx+dx)*40 + kb];
      a00 = MFMA16(wA,x0,a00); a01 = MFMA16(wA,x1,a01);
      a02 = MFMA16(wA,x2,a02); a03 = MFMA16(wA,x3,a03);
      a10 = MFMA16(wB,x0,a10); a11 = MFMA16(wB,x1,a11);
      a12 = MFMA16(wB,x2,a12); a13 = MFMA16(wB,x3,a13);
    }
  }
  const int ocl = (lane>>4)*4;
  #define DOG(G, A0,A1,A2,A3) { \
    const int oc0g = ocb + G*16 + ocl; \
    float bj0=bias[oc0g], bj1=bias[oc0g+1], bj2=bias[oc0g+2], bj3=bias[oc0g+3]; \
    float v00=A0[0]+bj0, v01=A0[1]+bj1, v02=A0[2]+bj2, v03=A0[3]+bj3; \
    float v10=A1[0]+bj0, v11=A1[1]+bj1, v12=A1[2]+bj2, v13=A1[3]+bj3; \
    float v20=A2[0]+bj0, v21=A2[1]+bj1, v22=A2[2]+bj2, v23=A2[3]+bj3; \
    float v30=A3[0]+bj0, v31=A3[1]+bj1, v32=A3[2]+bj2, v33=A3[3]+bj3; \
    float s0=v00+v10+v20+v30, q0=v00*v00+v10*v10+v20*v20+v30*v30; \
    float s1=v01+v11+v21+v31, q1=v01*v01+v11*v11+v21*v21+v31*v31; \
    float s2=v02+v12+v22+v32, q2=v02*v02+v12*v12+v22*v22+v32*v32; \
    float s3=v03+v13+v23+v33, q3=v03*v03+v13*v13+v23*v23+v33*v33; \
    s0+=__shfl_xor(s0,1,64); s0+=__shfl_xor(s0,2,64); s0+=__shfl_xor(s0,4,64); s0+=__shfl_xor(s0,8,64); \
    q0+=__shfl_xor(q0,1,64); q0+=__shfl_xor(q0,2,64); q0+=__shfl_xor(q0,4,64); q0+=__shfl_xor(q0,8,64); \
    s1+=__shfl_xor(s1,1,64); s1+=__shfl_xor(s1,2,64); s1+=__shfl_xor(s1,4,64); s1+=__shfl_xor(s1,8,64); \
    q1+=__shfl_xor(q1,1,64); q1+=__shfl_xor(q1,2,64); q1+=__shfl_xor(q1,4,64); q1+=__shfl_xor(q1,8,64); \
    s2+=__shfl_xor(s2,1,64); s2+=__shfl_xor(s2,2,64); s2+=__shfl_xor(s2,4,64); s2+=__shfl_xor(s2,8,64); \
    q2+=__shfl_xor(q2,1,64); q2+=__shfl_xor(q2,2,64); q2+=__shfl_xor(q2,4,64); q2+=__shfl_xor(q2,8,64); \
    s3+=__shfl_xor(s3,1,64); s3+=__shfl_xor(s3,2,64); s3+=__shfl_xor(s3,4,64); s3+=__shfl_xor(s3,8,64); \
    q3+=__shfl_xor(q3,1,64); q3+=__shfl_xor(q3,2,64); q3+=__shfl_xor(q3,4,64); q3+=__shfl_xor(q3,8,64); \
    if (colx==0){ \
      atomicAdd(&ss[oc0g],s0);   atomicAdd(&sq[oc0g],q0); \
      atomicAdd(&ss[oc0g+1],s1); atomicAdd(&sq[oc0g+1],q1); \
      atomicAdd(&ss[oc0g+2],s2); atomicAdd(&sq[oc0g+2],q2); \
      atomicAdd(&ss[oc0g+3],s3); atomicAdd(&sq[oc0g+3],q3); \
    } \
    if (outh){ \
      size_t pb = (size_t)((b<<16) + tX + colx); \
      *(short4*)&outh[(pb + ((tY+ry+0)<<8))*64 + oc0g] = make_short4(to_bf16(v00),to_bf16(v01),to_bf16(v02),to_bf16(v03)); \
      *(short4*)&outh[(pb + ((tY+ry+1)<<8))*64 + oc0g] = make_short4(to_bf16(v10),to_bf16(v11),to_bf16(v12),to_bf16(v13)); \
      *(short4*)&outh[(pb + ((tY+ry+2)<<8))*64 + oc0g] = make_short4(to_bf16(v20),to_bf16(v21),to_bf16(v22),to_bf16(v23)); \
      *(short4*)&outh[(pb + ((tY+ry+3)<<8))*64 + oc0g] = make_short4(to_bf16(v30),to_bf16(v31),to_bf16(v32),to_bf16(v33)); \
    } else { \
      size_t cb0 = (((size_t)(b*64+oc0g))<<16) + ((tY+ry)<<8) + tX + colx; \
      outf[cb0          ] = v00; outf[cb0+(1<<16)      ] = v01; outf[cb0+(2<<16)      ] = v02; outf[cb0+(3<<16)      ] = v03; \
      outf[cb0+256      ] = v10; outf[cb0+(1<<16)+256  ] = v11; outf[cb0+(2<<16)+256  ] = v12; outf[cb0+(3<<16)+256  ] = v13; \
      outf[cb0+512      ] = v20; outf[cb0+(1<<16)+512  ] = v21; outf[cb0+(2<<16)+512  ] = v22; outf[cb0+(3<<16)+512  ] = v23; \
      outf[cb0+768      ] = v30; outf[cb0+(1<<16)+768  ] = v31; outf[cb0+(2<<16)+768  ] = v32; outf[cb0+(3<<16)+768  ] = v33; \
    } \
  }
  DOG(0, a00,a01,a02,a03)
  DOG(1, a10,a11,a12,a13)
  #undef DOG
  __syncthreads();
  if (t < 64){
    atomicAdd(&stat[t],    ss[t]);
    atomicAdd(&stat[64+t], sq[t]);
  }
}

// bn_fin fused: computes sc/sh from raw stats in LDS, then applies BN+relu.
__global__ __launch_bounds__(256) void bn_apply(float* __restrict__ x, const float* __restrict__ bnst,
                                                const float* __restrict__ g, const float* __restrict__ be){
  __shared__ float sBN[128];
  if (threadIdx.x < 64){
    int c = threadIdx.x;
    const float n = 131072.f;
    float m = bnst[c]/n;
    float v = fmaxf(bnst[64+c]/n - m*m, 0.f);
    float sc = g[c]*rsqrtf(v+1e-5f);
    sBN[c]=sc; sBN[64+c]=be[c]-m*sc;
  }
  __syncthreads();
  size_t idx = (size_t)blockIdx.x*256 + threadIdx.x;
  size_t stride = (size_t)gridDim.x*256;
  float4* p = (float4*)x;
  for (size_t k=idx; k<2097152ULL; k+=stride){
    int c = (int)((k>>14)&63);
    float sc = sBN[c], sh = sBN[64+c];
    float4 v = p[k];
    v.x=fmaxf(v.x*sc+sh,0.f); v.y=fmaxf(v.y*sc+sh,0.f);
    v.z=fmaxf(v.z*sc+sh,0.f); v.w=fmaxf(v.w*sc+sh,0.f);
    p[k]=v;
  }
}

// ---------------- launch ----------------
extern "C" void kernel_launch(void* const* d_in, const int* in_sizes, int n_in,
                              void* d_out, int out_size, void* d_ws, size_t ws_size,
                              hipStream_t stream){
  const float* pts  = (const float*)d_in[0];
  const void*  mask = d_in[1];
  const float* w1 = (const float*)d_in[2];
  const float* b1 = (const float*)d_in[3];
  const float* g1 = (const float*)d_in[4];
  const float* be1= (const float*)d_in[5];
  const float* w2 = (const float*)d_in[6];
  const float* b2 = (const float*)d_in[7];
  const float* g2 = (const float*)d_in[8];
  const float* be2= (const float*)d_in[9];
  const float* cw[3]  = {(const float*)d_in[10],(const float*)d_in[14],(const float*)d_in[18]};
  const float* cb[3]  = {(const float*)d_in[11],(const float*)d_in[15],(const float*)d_in[19]};
  const float* cg[3]  = {(const float*)d_in[12],(const float*)d_in[16],(const float*)d_in[20]};
  const float* cbe[3] = {(const float*)d_in[13],(const float*)d_in[17],(const float*)d_in[21]};
  float* out = (float*)d_out;

  char* W = (char*)d_ws;
  size_t off = 0;
  auto A = [&](size_t n){ size_t r = off; off = (off + n + 255) & ~(size_t)255; return r; };
  short*    BIGH  = (short*)   (W + A((size_t)2*NCELL*64*2));
  short*    OUT1H = (short*)   (W + A((size_t)2*NCELL*64*2));
  int*      PID   = (int*)     (W + A((size_t)2*NPTS*4));
  int*      CRANK = (int*)     (W + A((size_t)2*NCELL*4));
  int*      CSTART= (int*)     (W + A((size_t)2*NCELL*4));
  int*      PLIST = (int*)     (W + A((size_t)2*NPTS*4));
  int*      PCELL = (int*)     (W + A((size_t)2*MAXP*4));
  float*    CPTS  = (float*)   (W + A((size_t)2*NPTS*12*4));
  float*    TBUF  = (float*)   (W + A((size_t)2*NPTS*64*4));
  unsigned* FMN   = (unsigned*)(W + A((size_t)2*MAXP*64*4));
  short*    WH    = (short*)   (W + A((size_t)3*36864*2));
  short*    W1H   = (short*)   (W + A((size_t)2048*2));
  short*    W2H   = (short*)   (W + A((size_t)4096*2));
  int2*     BPART = (int2*)    (W + A((size_t)2*64*8));
  // ---- zero block ----
  size_t zbeg = off;
  unsigned* FMX   = (unsigned*)(W + A((size_t)2*MAXP*64*4));
  int*      CCNT  = (int*)     (W + A((size_t)2*NCELL*4));
  int*      CTMP  = (int*)     (W + A((size_t)2*NCELL*4));
  float*    PSUM  = (float*)   (W + A((size_t)2*MAXP*16));
  float*    LSTAT = (float*)   (W + A((size_t)16*2*65*4));
  float*    L2STAT= (float*)   (W + A((size_t)16*2*2*64*4));
  float*    BNST  = (float*)   (W + A((size_t)3*256*4));
  int*      HEAVY = (int*)     (W + A((size_t)(2+2*64)*4));
  int*      MISC  = (int*)     (W + A(256));
  size_t zend = off;

  prep<<<2048,256,0,stream>>>((uint4*)BIGH, (size_t)2*NCELL*64*2/16,
                              (uint4*)(W+zbeg), (zend-zbeg)/16,
                              cw[0], cw[1], cw[2], WH, w1, w2, W1H, W2H,
                              (uint4*)FMN, (size_t)2*MAXP*64*4/16);

  dim3 perPt((NPTS+255)/256, 2);

  compute_pid<<<perPt,256,0,stream>>>(pts, mask, PID, CCNT);
  scan_a<<<dim3(64,2),256,0,stream>>>(CCNT, BPART);
  scan_b<<<dim3(64,2),256,0,stream>>>(CCNT, BPART, CRANK, CSTART, PCELL, MISC, HEAVY);
  scatter_cpts<<<perPt,256,0,stream>>>(pts, PID, CCNT, CRANK, CSTART, CTMP, PLIST, CPTS, PSUM);
  heavy_select<<<dim3(64,2),64,0,stream>>>(pts, CCNT, CRANK, CSTART, PLIST, HEAVY, CPTS, PSUM);
  moments<<<dim3(120,2),256,0,stream>>>(CPTS, PSUM, MISC, LSTAT);
  point_mlp<<<dim3(256,2),256,0,stream>>>(CPTS, MISC, w1, b1, g1, be1,
                                          W1H, W2H, LSTAT, TBUF);
  seg_max<<<dim3(938,2),256,0,stream>>>(TBUF, CPTS, MISC, L2STAT, FMX, FMN);
  scatter_bev<<<dim3(512,2),256,0,stream>>>(w1, b1, g1, be1, w2, b2, g2, be2,
                                            LSTAT, L2STAT, FMX, FMN, PCELL, MISC, BIGH);

  // conv1: BIGH -> OUT1H (bf16, raw) + stats BNST0
  conv_mfma<<<dim3(16,16,2),512,0,stream>>>(BIGH, WH, cb[0], nullptr, nullptr, nullptr,
                                            OUT1H, nullptr, BNST);
  // conv2: OUT1H (bn1+relu in-kernel from BNST0) -> BIGH + stats BNST1
  conv_mfma<<<dim3(16,16,2),512,0,stream>>>(OUT1H, WH+36864, cb[1], BNST, cg[0], cbe[0],
                                            BIGH, nullptr, BNST+256);
  // conv3: BIGH (bn2+relu from BNST1) -> d_out (fp32) + stats BNST2
  conv_mfma<<<dim3(16,16,2),512,0,stream>>>(BIGH, WH+2*36864, cb[2], BNST+256, cg[1], cbe[1],
                                            nullptr, out, BNST+512);
  bn_apply<<<2048,256,0,stream>>>(out, BNST+512, cg[2], cbe[2]);
}

// Round 20
// 213.882 us; speedup vs baseline: 1.0596x; 1.0063x over previous
//
#include <hip/hip_runtime.h>

#define NPTS 60000
#define NXG 256
#define NCELL 65536
#define MAXP 12000
#define MAXPP 32
#define NROWS (MAXP*MAXPP)

typedef float f32x32 __attribute__((ext_vector_type(32)));
typedef float f32x4  __attribute__((ext_vector_type(4)));
typedef short s16x8  __attribute__((ext_vector_type(8)));

__device__ __forceinline__ short to_bf16(float f){
  unsigned u = __float_as_uint(f);
  unsigned r = (u + 0x7FFFu + ((u>>16)&1u)) >> 16;
  return (short)r;
}
// order-preserving float<->uint for atomicMax/Min
__device__ __forceinline__ unsigned mapf(float f){
  unsigned u = __float_as_uint(f);
  return (u & 0x80000000u) ? ~u : (u | 0x80000000u);
}
__device__ __forceinline__ float unmapf(unsigned u){
  unsigned b = (u & 0x80000000u) ? (u ^ 0x80000000u) : ~u;
  return __uint_as_float(b);
}

// ---------------- prep: zero ws + conv/mlp weights bf16 + FMN pattern ----------------
__global__ __launch_bounds__(256) void prep(uint4* __restrict__ p1, size_t n1,
                                            uint4* __restrict__ p2, size_t n2,
                                            const float* __restrict__ w0, const float* __restrict__ w1,
                                            const float* __restrict__ w2, short* __restrict__ wh,
                                            const float* __restrict__ mw1, const float* __restrict__ mw2,
                                            short* __restrict__ w1h, short* __restrict__ w2h,
                                            uint4* __restrict__ fmn, size_t nfmn){
  size_t idx = (size_t)blockIdx.x*256 + threadIdx.x;
  size_t stride = (size_t)gridDim.x*256;
  const uint4 z = make_uint4(0,0,0,0);
  const uint4 ff = make_uint4(0xFFFFFFFFu,0xFFFFFFFFu,0xFFFFFFFFu,0xFFFFFFFFu);
  for (size_t k=idx; k<n1; k+=stride) p1[k]=z;
  for (size_t k=idx; k<n2; k+=stride) p2[k]=z;
  for (size_t k=idx; k<nfmn; k+=stride) fmn[k]=ff;
  for (size_t k=idx; k<3*36864; k+=stride){
    int l = (int)(k / 36864), r = (int)(k - (size_t)l*36864);
    const float* w = (l==0)? w0 : ((l==1)? w1 : w2);
    int ic = r & 63, oc = (r>>6)&63, tap = r>>12;
    wh[k] = to_bf16(w[(oc*64+ic)*9 + tap]);
  }
  for (size_t k=idx; k<2048; k+=stride){           // w1h: [k(32, zero-pad>=10)][oc]
    int kk = (int)(k>>6), oc = (int)(k&63);
    w1h[k] = (kk<10) ? to_bf16(mw1[kk*64+oc]) : (short)0;
  }
  for (size_t k=idx; k<4096; k+=stride)            // w2h: [k(64)][oc]
    w2h[k] = to_bf16(mw2[k]);
}

// ---------------- pillarize (mask dtype probed per-block) ----------------
__global__ void compute_pid(const float* __restrict__ pts, const void* __restrict__ maskp,
                            int* __restrict__ pid, int* __restrict__ ccnt){
  __shared__ int cf32, cbig;
  if (threadIdx.x==0){ cf32=0; cbig=0; }
  __syncthreads();
  {
    int lf=0, lb=0;
    const unsigned* mu = (const unsigned*)maskp;
    for (int k=0;k<4;k++){
      unsigned x = mu[threadIdx.x*4+k];
      if (x==0x3f800000u) lf++;
      else if (x>1u) lb++;
    }
    if (lf) atomicAdd(&cf32, lf);
    if (lb) atomicAdd(&cbig, lb);
  }
  __syncthreads();
  int mode = (cf32>64) ? 2 : ((cbig>0) ? 1 : 0);
  int i = blockIdx.x*blockDim.x + threadIdx.x;
  if (i>=NPTS) return;
  int b = blockIdx.y;
  int gi = b*NPTS+i;
  bool m;
  if (mode==0)      m = ((const int*)maskp)[gi]!=0;
  else if (mode==1) m = ((const unsigned char*)maskp)[gi]!=0;
  else              m = ((const float*)maskp)[gi]!=0.f;
  int cell = -1;
  if (m){
    float x = pts[(size_t)gi*5+0], y = pts[(size_t)gi*5+1];
    int ix = (int)((x - (-32.0f)) / 0.25f);
    ix = ix<0?0:(ix>255?255:ix);
    int iy = (int)((y - (-32.0f)) / 0.25f);
    iy = iy<0?0:(iy>255?255:iy);
    cell = iy*NXG + ix;
    atomicAdd(&ccnt[b*NCELL+cell], 1);
  }
  pid[gi] = cell;
}

// ---------------- parallel occupancy scan ----------------
__global__ __launch_bounds__(256) void scan_a(const int* __restrict__ ccnt,
                                              int2* __restrict__ bpart){
  int b = blockIdx.y, blk = blockIdx.x, t = threadIdx.x;
  int4 v = *(const int4*)&ccnt[b*NCELL + blk*1024 + t*4];
  int occ = (v.x>0)+(v.y>0)+(v.z>0)+(v.w>0);
  int cnt = v.x+v.y+v.z+v.w;
  #pragma unroll
  for (int off=32; off>0; off>>=1){
    occ += __shfl_xor(occ, off, 64);
    cnt += __shfl_xor(cnt, off, 64);
  }
  __shared__ int so[4], sc[4];
  int wv = t>>6, lane = t&63;
  if (lane==0){ so[wv]=occ; sc[wv]=cnt; }
  __syncthreads();
  if (t==0) bpart[b*64+blk] = make_int2(so[0]+so[1]+so[2]+so[3], sc[0]+sc[1]+sc[2]+sc[3]);
}

__global__ __launch_bounds__(256) void scan_b(const int* __restrict__ ccnt,
    const int2* __restrict__ bpart,
    int* __restrict__ crank, int* __restrict__ cstart, int* __restrict__ pcell,
    int* __restrict__ misc, int* __restrict__ heavy){
  __shared__ int swo[4], swc[4], sk[4];
  __shared__ int bo_, bc_;
  int b = blockIdx.y, blk = blockIdx.x, t = threadIdx.x;
  int wv = t>>6, lane = t&63;
  if (t < 64){
    int2 p = bpart[b*64+t];
    int po = (t<blk)? p.x : 0;
    int pc = (t<blk)? p.y : 0;
    int to = p.x;
    int tc = p.y;
    #pragma unroll
    for (int off=32; off>0; off>>=1){
      po += __shfl_xor(po, off, 64);
      pc += __shfl_xor(pc, off, 64);
      to += __shfl_xor(to, off, 64);
      tc += __shfl_xor(tc, off, 64);
    }
    if (t==0){
      bo_ = po; bc_ = pc;
      if (blk==0){
        misc[1+b] = (to < MAXP) ? to : MAXP;
        misc[5+b] = tc;               // total masked points
      }
    }
  }
  int4 v = *(const int4*)&ccnt[b*NCELL + blk*1024 + t*4];
  int occ = (v.x>0)+(v.y>0)+(v.z>0)+(v.w>0);
  int cnt = v.x+v.y+v.z+v.w;
  int io = occ, ic = cnt;
  #pragma unroll
  for (int off=1; off<64; off<<=1){
    int ao = __shfl_up(io, off, 64);
    int ac = __shfl_up(ic, off, 64);
    if (lane >= off){ io += ao; ic += ac; }
  }
  if (lane==63){ swo[wv]=io; swc[wv]=ic; }
  __syncthreads();
  int wvo=0, wvc=0;
  #pragma unroll
  for (int w2=0; w2<4; w2++){
    if (w2<wv){ wvo += swo[w2]; wvc += swc[w2]; }
  }
  int eo = bo_ + wvo + io - occ;
  int ec = bc_ + wvc + ic - cnt;
  int kept = 0;
  int cellb = blk*1024 + t*4;
  int vv[4] = {v.x,v.y,v.z,v.w};
  #pragma unroll
  for (int j=0;j<4;j++){
    int c = cellb+j; int val = vv[j];
    if (val>0){
      crank[b*NCELL+c]=eo; cstart[b*NCELL+c]=ec;
      if (eo<MAXP){
        pcell[b*MAXP+eo]=c;
        kept += (val<MAXPP)? val : MAXPP;
        if (val>MAXPP){
          int hi = atomicAdd(&heavy[b],1);
          if (hi<64) heavy[2 + b*64 + hi] = c;
        }
      }
      eo++; ec+=val;
    }
  }
  #pragma unroll
  for (int off=32; off>0; off>>=1) kept += __shfl_xor(kept, off, 64);
  if (lane==0) sk[wv]=kept;
  __syncthreads();
  if (t==0) atomicAdd(&misc[3+b], sk[0]+sk[1]+sk[2]+sk[3]);
}

// ---------------- scatter: write CPTS directly at pillar-sorted position ----------------
// CPTS[pos]: [x,y,z,i1][i2,gx,gy,rid][dx,dy,dz,0]  (quad2 filled by moments)
__global__ void scatter_cpts(const float* __restrict__ pts, const int* __restrict__ pid,
    const int* __restrict__ ccnt, const int* __restrict__ crank, const int* __restrict__ cstart,
    int* __restrict__ ctmp, int* __restrict__ plist,
    float* __restrict__ cpts, float* __restrict__ psum, int* __restrict__ rida){
  int i = blockIdx.x*blockDim.x + threadIdx.x;
  if (i>=NPTS) return;
  int b = blockIdx.y;
  int gi = b*NPTS+i;
  int cell = pid[gi];
  if (cell<0) return;
  int bc = b*NCELL+cell;
  int pos = cstart[bc] + atomicAdd(&ctmp[bc],1);
  plist[b*NPTS+pos] = i;
  int cnt = ccnt[bc], r = crank[bc];
  int rid = (r<MAXP && cnt<=MAXPP) ? r : -1;
  const float* qp = &pts[(size_t)gi*5];
  float x=qp[0], y=qp[1], z=qp[2], i1=qp[3], i2=qp[4];
  float gx = -32.0f + ((float)(cell&255)+0.5f)*0.25f;
  float gy = -32.0f + ((float)(cell>>8)+0.5f)*0.25f;
  float4* cp = (float4*)&cpts[(size_t)(b*NPTS+pos)*12];
  cp[0] = make_float4(x,y,z,i1);
  cp[1] = make_float4(i2,gx,gy,__int_as_float(rid));
  rida[b*NPTS+pos] = rid;
  if (rid>=0){
    float* s = &psum[(size_t)(b*MAXP+rid)*4];
    atomicAdd(s+0,x); atomicAdd(s+1,y); atomicAdd(s+2,z); atomicAdd(s+3,1.f);
  }
}

// heavy cells (>32 pts): select first-32-by-original-index, patch CPTS rid + psum
__global__ void heavy_select(const float* __restrict__ pts,
    const int* __restrict__ ccnt, const int* __restrict__ crank,
    const int* __restrict__ cstart, const int* __restrict__ plist,
    const int* __restrict__ heavy, float* __restrict__ cpts, float* __restrict__ psum,
    int* __restrict__ rida){
  int b = blockIdx.y;
  int hn = heavy[b]; if (hn>64) hn=64;
  if ((int)blockIdx.x >= hn) return;
  int cell = heavy[2 + b*64 + blockIdx.x];
  int bc = b*NCELL+cell;
  int cnt = ccnt[bc], start = cstart[bc], pr = crank[bc];
  for (int e=threadIdx.x; e<cnt; e+=blockDim.x){
    int pe = plist[b*NPTS+start+e];
    int rank=0;
    for (int k=0;k<cnt;k++) rank += (plist[b*NPTS+start+k] < pe);
    if (rank<MAXPP && pr<MAXP){
      cpts[(size_t)(b*NPTS+start+e)*12 + 7] = __int_as_float(pr);
      rida[b*NPTS+start+e] = pr;
      const float* qp = &pts[(size_t)(b*NPTS+pe)*5];
      float* s = &psum[(size_t)(b*MAXP+pr)*4];
      atomicAdd(s+0,qp[0]); atomicAdd(s+1,qp[1]); atomicAdd(s+2,qp[2]); atomicAdd(s+3,1.f);
    }
  }
}

// ---------------- global aug moments (65 register accumulators) + centroid writeback ----
#define MM_ACC(K,V) { if ((K)<32) m0[(K)&31]+=(V); else if ((K)<64) m1[((K)-32)&31]+=(V); else m2+=(V); }
__global__ __launch_bounds__(256) void moments(float* __restrict__ cpts,
    const float* __restrict__ psum, const int* __restrict__ misc,
    float* __restrict__ lstat){
  int b = blockIdx.y;
  int n = misc[5+b];
  f32x32 m0, m1; float m2 = 0.f;
  #pragma unroll
  for (int j=0;j<32;j++){ m0[j]=0.f; m1[j]=0.f; }
  for (int pos = blockIdx.x*256+threadIdx.x; pos<n; pos += gridDim.x*256){
    float4* cp = (float4*)&cpts[(size_t)(b*NPTS+pos)*12];
    float4 f1 = cp[0], f2 = cp[1];
    int rid = __float_as_int(f2.w);
    if (rid<0) continue;
    float4 mc = *(const float4*)&psum[(size_t)(b*MAXP+rid)*4];
    float inv = 1.f/fmaxf(mc.w,1.f);
    float dx = f1.x-mc.x*inv, dy = f1.y-mc.y*inv, dz = f1.z-mc.z*inv;
    cp[2] = make_float4(dx,dy,dz,0.f);
    float aug[10] = {f1.x,f1.y,f1.z,f1.w,f2.x, dx,dy,dz, f2.y,f2.z};
    #pragma unroll
    for (int d=0; d<10; d++){
      #pragma unroll
      for (int e=d; e<10; e++){
        const int k = d*10 - d*(d-1)/2 + (e-d);
        MM_ACC(k, aug[d]*aug[e]);
      }
      const int kl = 55+d;
      MM_ACC(kl, aug[d]);
    }
  }
  int lane = threadIdx.x & 63;
  int rep = ((blockIdx.x*256+threadIdx.x)>>6) & 15;
  float* dst = &lstat[(size_t)(rep*2+b)*65];
  #pragma unroll
  for (int j=0;j<32;j++){
    float v = m0[j];
    #pragma unroll
    for (int off=32; off>0; off>>=1) v += __shfl_xor(v, off, 64);
    if (lane==0) atomicAdd(&dst[j], v);
  }
  #pragma unroll
  for (int j=0;j<32;j++){
    float v = m1[j];
    #pragma unroll
    for (int off=32; off>0; off>>=1) v += __shfl_xor(v, off, 64);
    if (lane==0) atomicAdd(&dst[32+j], v);
  }
  {
    float v = m2;
    #pragma unroll
    for (int off=32; off>0; off>>=1) v += __shfl_xor(v, off, 64);
    if (lane==0) atomicAdd(&dst[64], v);
  }
}

// ---------------- point-parallel MLP via MFMA: T[pos][64] = relu(bn1(Aug@W1))@W2 ----------
#define MFMA16(A,B,C) __builtin_amdgcn_mfma_f32_16x16x32_bf16(A,B,C,0,0,0)

__global__ __launch_bounds__(256) void point_mlp(const float* __restrict__ cpts,
    const int* __restrict__ misc,
    const float* __restrict__ w1, const float* __restrict__ b1,
    const float* __restrict__ g1, const float* __restrict__ be1,
    const short* __restrict__ w1h, const short* __restrict__ w2h,
    const float* __restrict__ lstat, float* __restrict__ tbuf){
  __shared__ float sM[65];
  __shared__ float sBN1[128];
  __shared__ short zT[4][16*72];
  const int b = blockIdx.y;
  const int t = threadIdx.x;
  for (int e=t; e<65; e+=256){
    float s=0.f;
    for (int r=0;r<16;r++) s += lstat[(size_t)(r*2+b)*65+e];
    sM[e]=s;
  }
  __syncthreads();
  if (t < 64){
    int c = t;
    float wcol[10];
    #pragma unroll
    for (int d=0;d<10;d++) wcol[d] = w1[d*64+c];
    float b1c = b1[c];
    float nk = (float)misc[3+b];
    const float N = (float)NROWS;
    float pad = N - nk;
    float lw = 0.f;
    #pragma unroll
    for (int d=0;d<10;d++) lw += sM[55+d]*wcol[d];
    float s = nk*b1c + lw;
    float qq = nk*b1c*b1c + 2.f*b1c*lw;
    #pragma unroll
    for (int d=0; d<10; d++){
      #pragma unroll
      for (int e=d; e<10; e++){
        float m = sM[d*10 - d*(d-1)/2 + (e-d)];
        qq += ((d==e)?1.f:2.f)*m*wcol[d]*wcol[e];
      }
    }
    float St = s + pad*b1c;
    float Qt = qq + pad*b1c*b1c;
    float mu = St/N;
    float var = fmaxf(Qt/N - mu*mu, 0.f);
    float sc = g1[c]*rsqrtf(var+1e-5f);
    float sh = be1[c]-mu*sc;
    sBN1[c]=sc; sBN1[64+c]=b1c*sc+sh;   // z = relu(y*sc + (b1*sc+sh)), y excludes b1
  }
  __syncthreads();
  const int lane = t & 63, wv = t >> 6;
  const int colx = lane & 15;
  const int kq = lane >> 4, kb = kq*8;
  s16x8 w1f0, w1f1, w1f2, w1f3;
  s16x8 a2f0, a2f1, a2f2, a2f3;
  s16x8 b2f0, b2f1, b2f2, b2f3;
  #pragma unroll
  for (int j=0;j<8;j++){
    w1f0[j]=w1h[(kb+j)*64 +  0+colx]; w1f1[j]=w1h[(kb+j)*64 + 16+colx];
    w1f2[j]=w1h[(kb+j)*64 + 32+colx]; w1f3[j]=w1h[(kb+j)*64 + 48+colx];
    a2f0[j]=w2h[(kb+j)*64 +  0+colx]; a2f1[j]=w2h[(kb+j)*64 + 16+colx];
    a2f2[j]=w2h[(kb+j)*64 + 32+colx]; a2f3[j]=w2h[(kb+j)*64 + 48+colx];
    b2f0[j]=w2h[(32+kb+j)*64 +  0+colx]; b2f1[j]=w2h[(32+kb+j)*64 + 16+colx];
    b2f2[j]=w2h[(32+kb+j)*64 + 32+colx]; b2f3[j]=w2h[(32+kb+j)*64 + 48+colx];
  }
  float sc1v0=sBN1[colx],    sh1v0=sBN1[64+colx];
  float sc1v1=sBN1[16+colx], sh1v1=sBN1[80+colx];
  float sc1v2=sBN1[32+colx], sh1v2=sBN1[96+colx];
  float sc1v3=sBN1[48+colx], sh1v3=sBN1[112+colx];
  const int n = misc[5+b];
  const int ntiles = (n+15)>>4;
  short* myZ = zT[wv];
  for (int tile = blockIdx.x*4 + wv; tile < ntiles; tile += gridDim.x*4){
    int pos0 = tile*16;
    int pos = pos0 + colx;
    float aug[10];
    #pragma unroll
    for (int d=0;d<10;d++) aug[d]=0.f;
    if (pos < n){
      const float4* cp = (const float4*)&cpts[(size_t)(b*NPTS+pos)*12];
      float4 f1 = cp[0], f2 = cp[1], f3 = cp[2];
      aug[0]=f1.x; aug[1]=f1.y; aug[2]=f1.z; aug[3]=f1.w; aug[4]=f2.x;
      aug[5]=f3.x; aug[6]=f3.y; aug[7]=f3.z;
      aug[8]=f2.y; aug[9]=f2.z;
    }
    s16x8 af;
    #pragma unroll
    for (int j=0;j<8;j++){
      float v = 0.f;
      if (kq==0) v = aug[j];
      else if (kq==1 && j<2) v = aug[8+j];
      af[j] = to_bf16(v);
    }
    f32x4 y0={0.f,0.f,0.f,0.f}, y1=y0, y2=y0, y3=y0;
    y0 = MFMA16(af, w1f0, y0);
    y1 = MFMA16(af, w1f1, y1);
    y2 = MFMA16(af, w1f2, y2);
    y3 = MFMA16(af, w1f3, y3);
    #pragma unroll
    for (int m=0;m<4;m++){
      int pr = (kq*4+m)*72;
      myZ[pr +  0+colx] = to_bf16(fmaxf(y0[m]*sc1v0+sh1v0, 0.f));
      myZ[pr + 16+colx] = to_bf16(fmaxf(y1[m]*sc1v1+sh1v1, 0.f));
      myZ[pr + 32+colx] = to_bf16(fmaxf(y2[m]*sc1v2+sh1v2, 0.f));
      myZ[pr + 48+colx] = to_bf16(fmaxf(y3[m]*sc1v3+sh1v3, 0.f));
    }
    s16x8 az0 = *(const s16x8*)&myZ[colx*72 + kb];
    s16x8 az1 = *(const s16x8*)&myZ[colx*72 + 32 + kb];
    f32x4 t0={0.f,0.f,0.f,0.f}, t1=t0, t2=t0, t3=t0;
    t0 = MFMA16(az0, a2f0, t0); t0 = MFMA16(az1, b2f0, t0);
    t1 = MFMA16(az0, a2f1, t1); t1 = MFMA16(az1, b2f1, t1);
    t2 = MFMA16(az0, a2f2, t2); t2 = MFMA16(az1, b2f2, t2);
    t3 = MFMA16(az0, a2f3, t3); t3 = MFMA16(az1, b2f3, t3);
    #pragma unroll
    for (int m=0;m<4;m++){
      int pm = pos0 + kq*4 + m;
      if (pm < n){
        float* dst = &tbuf[(size_t)(b*NPTS+pm)*64];
        dst[ 0+colx] = t0[m];
        dst[16+colx] = t1[m];
        dst[32+colx] = t2[m];
        dst[48+colx] = t3[m];
      }
    }
  }
}

// ---------------- segmented max/min over T (coalesced, directional atomics, prefetch) ----
__global__ __launch_bounds__(256) void seg_max(const float* __restrict__ tbuf,
    const int* __restrict__ rida, const float* __restrict__ g2,
    const int* __restrict__ misc,
    float* __restrict__ l2stat, unsigned* __restrict__ fmxU, unsigned* __restrict__ fmnU){
  const int b = blockIdx.y;
  const int lane = threadIdx.x & 63;
  const int n = misc[5+b];
  const int w = blockIdx.x*4 + (threadIdx.x>>6);
  const bool gpos = g2[lane] >= 0.f;       // sign(sc2) == sign(g2); pick the atomic that is read
  float s2 = 0.f, q2 = 0.f;
  int p0 = w*16;
  if (p0 < n){
    int p1 = p0+16; if (p1>n) p1=n;
    int cur = -1;
    float tmax = -1e30f, tmin = 1e30f;
    int rid = rida[b*NPTS+p0];
    float tv = tbuf[(size_t)(b*NPTS+p0)*64 + lane];
    for (int pos=p0; pos<p1; ++pos){
      int nrid = -1; float ntv = 0.f;
      if (pos+1 < p1){
        nrid = rida[b*NPTS+pos+1];
        ntv = tbuf[(size_t)(b*NPTS+pos+1)*64 + lane];
      }
      if (rid >= 0){
        if (rid != cur){
          if (cur >= 0){
            size_t idx = (size_t)(b*MAXP+cur)*64 + lane;
            if (gpos) atomicMax(&fmxU[idx], mapf(tmax));
            else      atomicMin(&fmnU[idx], mapf(tmin));
          }
          cur = rid; tmax = -1e30f; tmin = 1e30f;
        }
        tmax = fmaxf(tmax, tv);
        tmin = fminf(tmin, tv);
        s2 += tv; q2 += tv*tv;
      }
      rid = nrid; tv = ntv;
    }
    if (cur >= 0){
      size_t idx = (size_t)(b*MAXP+cur)*64 + lane;
      if (gpos) atomicMax(&fmxU[idx], mapf(tmax));
      else      atomicMin(&fmnU[idx], mapf(tmin));
    }
  }
  int rep = w & 15;
  atomicAdd(&l2stat[(size_t)((rep*2+b)*2+0)*64+lane], s2);
  atomicAdd(&l2stat[(size_t)((rep*2+b)*2+1)*64+lane], q2);
}

// ---------------- BN2 params (in-block) + BN2+relu on pillar max/min -> bf16 BEV ----------
__global__ __launch_bounds__(256) void scatter_bev(
    const float* __restrict__ w1, const float* __restrict__ b1,
    const float* __restrict__ g1, const float* __restrict__ be1,
    const float* __restrict__ w2, const float* __restrict__ b2,
    const float* __restrict__ g2, const float* __restrict__ be2,
    const float* __restrict__ lstat, const float* __restrict__ l2stat,
    const unsigned* __restrict__ fmxU, const unsigned* __restrict__ fmnU,
    const int* __restrict__ pcell, const int* __restrict__ misc,
    short* __restrict__ bevh){
  __shared__ float M[65];
  __shared__ float z0s[64];
  __shared__ float sBN2[128];
  const int b = blockIdx.y;
  for (int e=threadIdx.x; e<65; e+=256){
    float s=0.f;
    for (int r=0;r<16;r++) s += lstat[(size_t)(r*2+b)*65+e];
    M[e]=s;
  }
  __syncthreads();
  if (threadIdx.x < 64){
    int c = threadIdx.x;
    float wcol[10];
    #pragma unroll
    for (int d=0;d<10;d++) wcol[d] = w1[d*64+c];
    float b1c = b1[c];
    float nk = (float)misc[3+b];
    const float N = (float)NROWS;
    float pad = N - nk;
    float lw = 0.f;
    #pragma unroll
    for (int d=0;d<10;d++) lw += M[55+d]*wcol[d];
    float s = nk*b1c + lw;
    float qq = nk*b1c*b1c + 2.f*b1c*lw;
    #pragma unroll
    for (int d=0; d<10; d++){
      #pragma unroll
      for (int e=d; e<10; e++){
        float m = M[d*10 - d*(d-1)/2 + (e-d)];
        qq += ((d==e)?1.f:2.f)*m*wcol[d]*wcol[e];
      }
    }
    float St = s + pad*b1c;
    float Qt = qq + pad*b1c*b1c;
    float mu = St/N;
    float var = fmaxf(Qt/N - mu*mu, 0.f);
    float sc1 = g1[c]*rsqrtf(var+1e-5f);
    float sh1 = be1[c]-mu*sc1;
    z0s[c] = fmaxf(b1c*sc1+sh1, 0.f);
  }
  __syncthreads();
  if (threadIdx.x < 64){
    int c = threadIdx.x;
    float nk = (float)misc[3+b];
    const float N = (float)NROWS;
    float pad = N - nk;
    float t0 = b2[c];
    for (int i2=0;i2<64;i2++) t0 += z0s[i2]*w2[(size_t)i2*64+c];
    float s2 = pad*t0, q2 = pad*t0*t0;
    for (int r=0;r<16;r++){
      s2 += l2stat[(size_t)((r*2+b)*2+0)*64+c];
      q2 += l2stat[(size_t)((r*2+b)*2+1)*64+c];
    }
    float m2 = s2/N;
    float v2 = fmaxf(q2/N - m2*m2, 0.f);
    float sc2 = g2[c]*rsqrtf(v2+1e-5f);
    sBN2[c]=sc2; sBN2[64+c]=be2[c]-m2*sc2;
  }
  __syncthreads();
  const int npil = misc[1+b];
  for (int tid = blockIdx.x*256+threadIdx.x; tid < 64*MAXP; tid += gridDim.x*256){
    int c = tid & 63;
    int p = tid >> 6;
    if (p >= npil) break;
    float sc2 = sBN2[c], sh2 = sBN2[64+c];
    size_t idx = (size_t)(b*MAXP+p)*64 + c;
    float tv = (sc2 >= 0.f) ? unmapf(fmxU[idx]) : unmapf(fmnU[idx]);
    float v = fmaxf(sc2*tv+sh2, 0.f);
    int cell = pcell[b*MAXP+p];
    bevh[((size_t)((b<<16) + cell))*64 + c] = to_bf16(v);
  }
}

// ---------------- fused MFMA conv3x3: one block per 16x16 tile, all 64 oc, 512 thr ----------
__global__ __launch_bounds__(512,4) void conv_mfma(const short* __restrict__ xh,
    const short* __restrict__ wh, const float* __restrict__ bias,
    const float* __restrict__ pstat, const float* __restrict__ pg, const float* __restrict__ pbe,
    short* __restrict__ outh, float* __restrict__ outf,
    float* __restrict__ stat){
  __shared__ short sX[324*40];
  __shared__ short sW[576*40];
  __shared__ float sBN[128];
  __shared__ float ss[64], sq[64];
  const int tX = blockIdx.x*16, tY = blockIdx.y*16;
  const int b = blockIdx.z;
  const int t = threadIdx.x;
  const int lane = t & 63, wv = t >> 6;
  const int colx = lane & 15;
  const int kb = (lane >> 4) * 8;
  const int ocb = (wv >> 2) * 32;
  const int ry  = (wv & 3) * 4;
  if (t < 64){ ss[t]=0.f; sq[t]=0.f; }
  if (t >= 64 && t < 128 && pstat){
    int c = t-64;
    const float n = 131072.f;
    float m = pstat[c]/n;
    float v = fmaxf(pstat[64+c]/n - m*m, 0.f);
    float sc = pg[c]*rsqrtf(v+1e-5f);
    sBN[c]=sc; sBN[64+c]=pbe[c]-m*sc;
  }

  f32x4 a00={0.f,0.f,0.f,0.f}, a01=a00, a02=a00, a03=a00;
  f32x4 a10=a00, a11=a00, a12=a00, a13=a00;

  for (int h=0; h<2; ++h){
    __syncthreads();
    for (int e=t; e<1296; e+=512){
      int px = e>>2, j = e&3;
      int yy = px/18, xx = px - yy*18;
      int gy = tY+yy-1, gx = tX+xx-1;
      uint4 v = make_uint4(0,0,0,0);
      if ((unsigned)gy<256u && (unsigned)gx<256u){
        v = *(const uint4*)&xh[((size_t)((b<<16) + (gy<<8) + gx))*64 + h*32 + j*8];
        if (pstat){
          unsigned arr[4] = {v.x, v.y, v.z, v.w};
          #pragma unroll
          for (int j2=0;j2<4;j2++){
            unsigned wrd = arr[j2];
            int ch = h*32 + j*8 + j2*2;
            float lo = __uint_as_float(wrd<<16);
            float hi = __uint_as_float(wrd & 0xffff0000u);
            lo = fmaxf(lo*sBN[ch]+sBN[64+ch], 0.f);
            hi = fmaxf(hi*sBN[ch+1]+sBN[64+ch+1], 0.f);
            arr[j2] = (unsigned)(unsigned short)to_bf16(lo) |
                      (((unsigned)(unsigned short)to_bf16(hi))<<16);
          }
          v = make_uint4(arr[0],arr[1],arr[2],arr[3]);
        }
      }
      *(uint4*)&sX[px*40 + j*8] = v;
    }
    for (int e=t; e<2304; e+=512){
      int row = e>>2, j = e&3;
      int tap = row>>6, oc = row&63;
      uint4 v = *(const uint4*)&wh[(size_t)tap*4096 + oc*64 + h*32 + j*8];
      *(uint4*)&sW[row*40 + j*8] = v;
    }
    __syncthreads();
    #pragma unroll
    for (int tap=0; tap<9; ++tap){
      const int dy = tap/3, dx = tap - dy*3;
      s16x8 wA = *(const s16x8*)&sW[(tap*64 + ocb +  0 + colx)*40 + kb];
      s16x8 wB = *(const s16x8*)&sW[(tap*64 + ocb + 16 + colx)*40 + kb];
      s16x8 x0 = *(const s16x8*)&sX[((ry+0+dy)*18 + colx+dx)*40 + kb];
      s16x8 x1 = *(const s16x8*)&sX[((ry+1+dy)*18 + colx+dx)*40 + kb];
      s16x8 x2 = *(const s16x8*)&sX[((ry+2+dy)*18 + colx+dx)*40 + kb];
      s16x8 x3 = *(const s16x8*)&sX[((ry+3+dy)*18 + colx+dx)*40 + kb];
      a00 = MFMA16(wA,x0,a00); a01 = MFMA16(wA,x1,a01);
      a02 = MFMA16(wA,x2,a02); a03 = MFMA16(wA,x3,a03);
      a10 = MFMA16(wB,x0,a10); a11 = MFMA16(wB,x1,a11);
      a12 = MFMA16(wB,x2,a12); a13 = MFMA16(wB,x3,a13);
    }
  }
  const int ocl = (lane>>4)*4;
  #define DOG(G, A0,A1,A2,A3) { \
    const int oc0g = ocb + G*16 + ocl; \
    float bj0=bias[oc0g], bj1=bias[oc0g+1], bj2=bias[oc0g+2], bj3=bias[oc0g+3]; \
    float v00=A0[0]+bj0, v01=A0[1]+bj1, v02=A0[2]+bj2, v03=A0[3]+bj3; \
    float v10=A1[0]+bj0, v11=A1[1]+bj1, v12=A1[2]+bj2, v13=A1[3]+bj3; \
    float v20=A2[0]+bj0, v21=A2[1]+bj1, v22=A2[2]+bj2, v23=A2[3]+bj3; \
    float v30=A3[0]+bj0, v31=A3[1]+bj1, v32=A3[2]+bj2, v33=A3[3]+bj3; \
    float s0=v00+v10+v20+v30, q0=v00*v00+v10*v10+v20*v20+v30*v30; \
    float s1=v01+v11+v21+v31, q1=v01*v01+v11*v11+v21*v21+v31*v31; \
    float s2=v02+v12+v22+v32, q2=v02*v02+v12*v12+v22*v22+v32*v32; \
    float s3=v03+v13+v23+v33, q3=v03*v03+v13*v13+v23*v23+v33*v33; \
    s0+=__shfl_xor(s0,1,64); s0+=__shfl_xor(s0,2,64); s0+=__shfl_xor(s0,4,64); s0+=__shfl_xor(s0,8,64); \
    q0+=__shfl_xor(q0,1,64); q0+=__shfl_xor(q0,2,64); q0+=__shfl_xor(q0,4,64); q0+=__shfl_xor(q0,8,64); \
    s1+=__shfl_xor(s1,1,64); s1+=__shfl_xor(s1,2,64); s1+=__shfl_xor(s1,4,64); s1+=__shfl_xor(s1,8,64); \
    q1+=__shfl_xor(q1,1,64); q1+=__shfl_xor(q1,2,64); q1+=__shfl_xor(q1,4,64); q1+=__shfl_xor(q1,8,64); \
    s2+=__shfl_xor(s2,1,64); s2+=__shfl_xor(s2,2,64); s2+=__shfl_xor(s2,4,64); s2+=__shfl_xor(s2,8,64); \
    q2+=__shfl_xor(q2,1,64); q2+=__shfl_xor(q2,2,64); q2+=__shfl_xor(q2,4,64); q2+=__shfl_xor(q2,8,64); \
    s3+=__shfl_xor(s3,1,64); s3+=__shfl_xor(s3,2,64); s3+=__shfl_xor(s3,4,64); s3+=__shfl_xor(s3,8,64); \
    q3+=__shfl_xor(q3,1,64); q3+=__shfl_xor(q3,2,64); q3+=__shfl_xor(q3,4,64); q3+=__shfl_xor(q3,8,64); \
    if (colx==0){ \
      atomicAdd(&ss[oc0g],s0);   atomicAdd(&sq[oc0g],q0); \
      atomicAdd(&ss[oc0g+1],s1); atomicAdd(&sq[oc0g+1],q1); \
      atomicAdd(&ss[oc0g+2],s2); atomicAdd(&sq[oc0g+2],q2); \
      atomicAdd(&ss[oc0g+3],s3); atomicAdd(&sq[oc0g+3],q3); \
    } \
    if (outh){ \
      size_t pb = (size_t)((b<<16) + tX + colx); \
      *(short4*)&outh[(pb + ((tY+ry+0)<<8))*64 + oc0g] = make_short4(to_bf16(v00),to_bf16(v01),to_bf16(v02),to_bf16(v03)); \
      *(short4*)&outh[(pb + ((tY+ry+1)<<8))*64 + oc0g] = make_short4(to_bf16(v10),to_bf16(v11),to_bf16(v12),to_bf16(v13)); \
      *(short4*)&outh[(pb + ((tY+ry+2)<<8))*64 + oc0g] = make_short4(to_bf16(v20),to_bf16(v21),to_bf16(v22),to_bf16(v23)); \
      *(short4*)&outh[(pb + ((tY+ry+3)<<8))*64 + oc0g] = make_short4(to_bf16(v30),to_bf16(v31),to_bf16(v32),to_bf16(v33)); \
    } else { \
      size_t cb0 = (((size_t)(b*64+oc0g))<<16) + ((tY+ry)<<8) + tX + colx; \
      outf[cb0          ] = v00; outf[cb0+(1<<16)      ] = v01; outf[cb0+(2<<16)      ] = v02; outf[cb0+(3<<16)      ] = v03; \
      outf[cb0+256      ] = v10; outf[cb0+(1<<16)+256  ] = v11; outf[cb0+(2<<16)+256  ] = v12; outf[cb0+(3<<16)+256  ] = v13; \
      outf[cb0+512      ] = v20; outf[cb0+(1<<16)+512  ] = v21; outf[cb0+(2<<16)+512  ] = v22; outf[cb0+(3<<16)+512  ] = v23; \
      outf[cb0+768      ] = v30; outf[cb0+(1<<16)+768  ] = v31; outf[cb0+(2<<16)+768  ] = v32; outf[cb0+(3<<16)+768  ] = v33; \
    } \
  }
  DOG(0, a00,a01,a02,a03)
  DOG(1, a10,a11,a12,a13)
  #undef DOG
  __syncthreads();
  if (t < 64){
    atomicAdd(&stat[t],    ss[t]);
    atomicAdd(&stat[64+t], sq[t]);
  }
}

// bn_fin fused: computes sc/sh from raw stats in LDS, then applies BN+relu.
__global__ __launch_bounds__(256) void bn_apply(float* __restrict__ x, const float* __restrict__ bnst,
                                                const float* __restrict__ g, const float* __restrict__ be){
  __shared__ float sBN[128];
  if (threadIdx.x < 64){
    int c = threadIdx.x;
    const float n = 131072.f;
    float m = bnst[c]/n;
    float v = fmaxf(bnst[64+c]/n - m*m, 0.f);
    float sc = g[c]*rsqrtf(v+1e-5f);
    sBN[c]=sc; sBN[64+c]=be[c]-m*sc;
  }
  __syncthreads();
  size_t idx = (size_t)blockIdx.x*256 + threadIdx.x;
  size_t stride = (size_t)gridDim.x*256;
  float4* p = (float4*)x;
  for (size_t k=idx; k<2097152ULL; k+=stride){
    int c = (int)((k>>14)&63);
    float sc = sBN[c], sh = sBN[64+c];
    float4 v = p[k];
    v.x=fmaxf(v.x*sc+sh,0.f); v.y=fmaxf(v.y*sc+sh,0.f);
    v.z=fmaxf(v.z*sc+sh,0.f); v.w=fmaxf(v.w*sc+sh,0.f);
    p[k]=v;
  }
}

// ---------------- launch ----------------
extern "C" void kernel_launch(void* const* d_in, const int* in_sizes, int n_in,
                              void* d_out, int out_size, void* d_ws, size_t ws_size,
                              hipStream_t stream){
  const float* pts  = (const float*)d_in[0];
  const void*  mask = d_in[1];
  const float* w1 = (const float*)d_in[2];
  const float* b1 = (const float*)d_in[3];
  const float* g1 = (const float*)d_in[4];
  const float* be1= (const float*)d_in[5];
  const float* w2 = (const float*)d_in[6];
  const float* b2 = (const float*)d_in[7];
  const float* g2 = (const float*)d_in[8];
  const float* be2= (const float*)d_in[9];
  const float* cw[3]  = {(const float*)d_in[10],(const float*)d_in[14],(const float*)d_in[18]};
  const float* cb[3]  = {(const float*)d_in[11],(const float*)d_in[15],(const float*)d_in[19]};
  const float* cg[3]  = {(const float*)d_in[12],(const float*)d_in[16],(const float*)d_in[20]};
  const float* cbe[3] = {(const float*)d_in[13],(const float*)d_in[17],(const float*)d_in[21]};
  float* out = (float*)d_out;

  char* W = (char*)d_ws;
  size_t off = 0;
  auto A = [&](size_t n){ size_t r = off; off = (off + n + 255) & ~(size_t)255; return r; };
  short*    BIGH  = (short*)   (W + A((size_t)2*NCELL*64*2));
  short*    OUT1H = (short*)   (W + A((size_t)2*NCELL*64*2));
  int*      PID   = (int*)     (W + A((size_t)2*NPTS*4));
  int*      CRANK = (int*)     (W + A((size_t)2*NCELL*4));
  int*      CSTART= (int*)     (W + A((size_t)2*NCELL*4));
  int*      PLIST = (int*)     (W + A((size_t)2*NPTS*4));
  int*      PCELL = (int*)     (W + A((size_t)2*MAXP*4));
  int*      RIDA  = (int*)     (W + A((size_t)2*NPTS*4));
  float*    CPTS  = (float*)   (W + A((size_t)2*NPTS*12*4));
  float*    TBUF  = (float*)   (W + A((size_t)2*NPTS*64*4));
  unsigned* FMN   = (unsigned*)(W + A((size_t)2*MAXP*64*4));
  short*    WH    = (short*)   (W + A((size_t)3*36864*2));
  short*    W1H   = (short*)   (W + A((size_t)2048*2));
  short*    W2H   = (short*)   (W + A((size_t)4096*2));
  int2*     BPART = (int2*)    (W + A((size_t)2*64*8));
  // ---- zero block ----
  size_t zbeg = off;
  unsigned* FMX   = (unsigned*)(W + A((size_t)2*MAXP*64*4));
  int*      CCNT  = (int*)     (W + A((size_t)2*NCELL*4));
  int*      CTMP  = (int*)     (W + A((size_t)2*NCELL*4));
  float*    PSUM  = (float*)   (W + A((size_t)2*MAXP*16));
  float*    LSTAT = (float*)   (W + A((size_t)16*2*65*4));
  float*    L2STAT= (float*)   (W + A((size_t)16*2*2*64*4));
  float*    BNST  = (float*)   (W + A((size_t)3*256*4));
  int*      HEAVY = (int*)     (W + A((size_t)(2+2*64)*4));
  int*      MISC  = (int*)     (W + A(256));
  size_t zend = off;

  prep<<<2048,256,0,stream>>>((uint4*)BIGH, (size_t)2*NCELL*64*2/16,
                              (uint4*)(W+zbeg), (zend-zbeg)/16,
                              cw[0], cw[1], cw[2], WH, w1, w2, W1H, W2H,
                              (uint4*)FMN, (size_t)2*MAXP*64*4/16);

  dim3 perPt((NPTS+255)/256, 2);

  compute_pid<<<perPt,256,0,stream>>>(pts, mask, PID, CCNT);
  scan_a<<<dim3(64,2),256,0,stream>>>(CCNT, BPART);
  scan_b<<<dim3(64,2),256,0,stream>>>(CCNT, BPART, CRANK, CSTART, PCELL, MISC, HEAVY);
  scatter_cpts<<<perPt,256,0,stream>>>(pts, PID, CCNT, CRANK, CSTART, CTMP, PLIST, CPTS, PSUM, RIDA);
  heavy_select<<<dim3(64,2),64,0,stream>>>(pts, CCNT, CRANK, CSTART, PLIST, HEAVY, CPTS, PSUM, RIDA);
  moments<<<dim3(120,2),256,0,stream>>>(CPTS, PSUM, MISC, LSTAT);
  point_mlp<<<dim3(256,2),256,0,stream>>>(CPTS, MISC, w1, b1, g1, be1,
                                          W1H, W2H, LSTAT, TBUF);
  seg_max<<<dim3(938,2),256,0,stream>>>(TBUF, RIDA, g2, MISC, L2STAT, FMX, FMN);
  scatter_bev<<<dim3(512,2),256,0,stream>>>(w1, b1, g1, be1, w2, b2, g2, be2,
                                            LSTAT, L2STAT, FMX, FMN, PCELL, MISC, BIGH);

  // conv1: BIGH -> OUT1H (bf16, raw) + stats BNST0
  conv_mfma<<<dim3(16,16,2),512,0,stream>>>(BIGH, WH, cb[0], nullptr, nullptr, nullptr,
                                            OUT1H, nullptr, BNST);
  // conv2: OUT1H (bn1+relu in-kernel from BNST0) -> BIGH + stats BNST1
  conv_mfma<<<dim3(16,16,2),512,0,stream>>>(OUT1H, WH+36864, cb[1], BNST, cg[0], cbe[0],
                                            BIGH, nullptr, BNST+256);
  // conv3: BIGH (bn2+relu from BNST1) -> d_out (fp32) + stats BNST2
  conv_mfma<<<dim3(16,16,2),512,0,stream>>>(BIGH, WH+2*36864, cb[2], BNST+256, cg[1], cbe[1],
                                            nullptr, out, BNST+512);
  bn_apply<<<2048,256,0,stream>>>(out, BNST+512, cg[2], cbe[2]);
}